// Round 6
// baseline (393.240 us; speedup 1.0000x reference)
//
#include <hip/hip_runtime.h>
#include <hip/hip_bf16.h>

typedef __attribute__((ext_vector_type(8))) short short8;
typedef __attribute__((ext_vector_type(4))) float f32x4;

#define TSEQ 2048
#define DMODEL 1024
#define NH 16
#define HD 64
#define PLANE 4194304   // floats per [4096][1024] plane

__device__ __forceinline__ ushort f2bf(float f) {
    union { float f; unsigned int u; } c; c.f = f;
    unsigned int u = c.u + 0x7fffu + ((c.u >> 16) & 1u);   // RNE
    return (ushort)(u >> 16);
}

__device__ __forceinline__ float bf2f(ushort u) {
    union { unsigned int i; float f; } c; c.i = ((unsigned int)u) << 16;
    return c.f;
}

// split fp32 into hi+lo bf16 (pair reproduces x to ~2^-17 relative)
__device__ __forceinline__ void split2(float x, ushort& h, ushort& l) {
    h = f2bf(x);
    float r = x - bf2f(h);
    l = f2bf(r);
}

__device__ __forceinline__ float silu_f(float y) {
    return y / (1.f + __expf(-y));
}

// async global->LDS (dest = wave-uniform base + lane*16)
__device__ __forceinline__ void gl_lds16(const float* g, float* l) {
    __builtin_amdgcn_global_load_lds(
        (__attribute__((address_space(1))) void*)g,
        (__attribute__((address_space(3))) void*)l, 16, 0, 0);
}
__device__ __forceinline__ void gl_lds16u(const ushort* g, ushort* l) {
    __builtin_amdgcn_global_load_lds(
        (__attribute__((address_space(1))) void*)g,
        (__attribute__((address_space(3))) void*)l, 16, 0, 0);
}

// ---------------- convert x -> bf16 ----------------
__global__ void gdn_cvt_x(const float* __restrict__ x, ushort* __restrict__ xb) {
    int i = blockIdx.x * 256 + threadIdx.x;           // one float4 per thread
    float4 v = ((const float4*)x)[i];
    ushort4 o;
    o.x = f2bf(v.x); o.y = f2bf(v.y); o.z = f2bf(v.z); o.w = f2bf(v.w);
    ((ushort4*)xb)[i] = o;
}

// ------------- transpose+convert weights: W[k][n] f32 -> wt[z][n][k] bf16 -------------
__global__ void gdn_cvt_w(const float* __restrict__ Wq, const float* __restrict__ Wk,
                          const float* __restrict__ Wv, const float* __restrict__ Wg,
                          const float* __restrict__ Wo, ushort* __restrict__ wt) {
    __shared__ float tile[32][33];
    int z = blockIdx.z;
    const float* W = (z == 0) ? Wq : (z == 1) ? Wk : (z == 2) ? Wv : (z == 3) ? Wg : Wo;
    int n0 = blockIdx.x * 32, k0 = blockIdx.y * 32;
    int tx = threadIdx.x, ty = threadIdx.y;           // (32, 8)
    #pragma unroll
    for (int j = 0; j < 32; j += 8)
        tile[ty + j][tx] = W[(size_t)(k0 + ty + j) * DMODEL + n0 + tx];
    __syncthreads();
    ushort* o = wt + (size_t)z * DMODEL * DMODEL;
    #pragma unroll
    for (int j = 0; j < 32; j += 8)
        o[(size_t)(n0 + ty + j) * DMODEL + k0 + tx] = f2bf(tile[tx][ty + j]);
}

// ---------------- betaT[(b*NH+h)*TSEQ + t] = sigmoid(x @ Wb), fp32 exact ----------------
__global__ void gdn_beta(const float* __restrict__ x, const float* __restrict__ Wb,
                         float* __restrict__ betaT) {
    __shared__ float xs[16][DMODEL];
    int tid = threadIdx.x;
    int m0 = blockIdx.x * 16;
    #pragma unroll
    for (int i = 0; i < 16; i++) {
        int idx = i * 256 + tid;                 // float4 index
        int row = idx >> 8, c4 = idx & 255;
        *(float4*)&xs[row][c4 * 4] =
            *(const float4*)&x[(size_t)(m0 + row) * DMODEL + c4 * 4];
    }
    __syncthreads();
    int h = tid & 15, mi = tid >> 4;
    float acc = 0.f;
    for (int k = 0; k < DMODEL; ++k)
        acc += xs[mi][k] * Wb[k * NH + h];
    int m = m0 + mi;
    int b = m >> 11, t = m & (TSEQ - 1);
    betaT[((b * NH + h) << 11) + t] = 1.f / (1.f + __expf(-acc));
}

// ---------------- bf16 MFMA GEMM (m97 structure, 128^2): used for the final GEMM ----------
#define BK 32
__global__ __launch_bounds__(256) void gdn_gemm(const ushort* __restrict__ A,
                                                const ushort* __restrict__ Bt,
                                                float* __restrict__ outF,
                                                size_t planeStride) {
    __shared__ ushort As[128 * BK];    // 8 KB, linear
    __shared__ ushort Bs[128 * BK];    // 8 KB, linear
    int tid = threadIdx.x;
    int lane = tid & 63, wid = tid >> 6;
    int wm = wid & 1, wn = wid >> 1;
    int l15 = lane & 15, quad = lane >> 4;
    int bm = blockIdx.x, bn = blockIdx.y;
    const int K = DMODEL;

    int e0 = wid, e1 = wid + 4;
    int srow0 = e0 * 16 + (lane >> 2), srow1 = e1 * 16 + (lane >> 2);
    int scol = (lane & 3) * 8;
    const ushort* Ag0 = A + (size_t)(bm * 128 + srow0) * K + scol;
    const ushort* Ag1 = A + (size_t)(bm * 128 + srow1) * K + scol;
    const ushort* Bg0 = Bt + (size_t)(bn * 128 + srow0) * K + scol;
    const ushort* Bg1 = Bt + (size_t)(bn * 128 + srow1) * K + scol;
    ushort* Al0 = As + e0 * 512;
    ushort* Al1 = As + e1 * 512;
    ushort* Bl0 = Bs + e0 * 512;
    ushort* Bl1 = Bs + e1 * 512;

    f32x4 acc[4][4];
    #pragma unroll
    for (int i = 0; i < 4; i++)
        #pragma unroll
        for (int j = 0; j < 4; j++)
            acc[i][j] = (f32x4){0.f, 0.f, 0.f, 0.f};

    for (int kt = 0; kt < K; kt += BK) {
        __syncthreads();
        gl_lds16u(Ag0 + kt, Al0);
        gl_lds16u(Ag1 + kt, Al1);
        gl_lds16u(Bg0 + kt, Bl0);
        gl_lds16u(Bg1 + kt, Bl1);
        __syncthreads();
        short8 af[4], bf[4];
        #pragma unroll
        for (int i = 0; i < 4; i++) {
            af[i] = *(const short8*)&As[(wm * 64 + i * 16 + l15) * BK + quad * 8];
            bf[i] = *(const short8*)&Bs[(wn * 64 + i * 16 + l15) * BK + quad * 8];
        }
        #pragma unroll
        for (int mt = 0; mt < 4; mt++)
            #pragma unroll
            for (int nt = 0; nt < 4; nt++)
                acc[mt][nt] = __builtin_amdgcn_mfma_f32_16x16x32_bf16(
                    af[mt], bf[nt], acc[mt][nt], 0, 0, 0);
    }

    #pragma unroll
    for (int mt = 0; mt < 4; mt++)
        #pragma unroll
        for (int nt = 0; nt < 4; nt++)
            #pragma unroll
            for (int r = 0; r < 4; r++) {
                int row = bm * 128 + wm * 64 + mt * 16 + quad * 4 + r;
                int col = bn * 128 + wn * 64 + nt * 16 + l15;
                outF[(size_t)(col >> 10) * planeStride + (size_t)row * 1024 + (col & 1023)]
                    = acc[mt][nt][r];
            }
}

// ------------- 256^2 GEMM, triple-buffered counted-vmcnt pipeline (big GEMM) -------------
// 8 waves (2M x 4N), per-wave 128x64 output. 3 LDS slots x (16KB A + 16KB B) = 96 KB.
// Prefetch lead = 2 K-tiles; per step: issue tile c+2 -> ds_read -> 32 MFMA ->
// s_waitcnt vmcnt(4) (tile c+1 resident, tile c+2 stays in flight) -> s_barrier.
// Slot (c+2)%3 was consumed at step c-1 (all waves passed that barrier) -> safe overwrite.
__global__ __launch_bounds__(512, 2) void gdn_gemm256(const ushort* __restrict__ A,
                                                      const ushort* __restrict__ Bt,
                                                      float* __restrict__ outF,
                                                      size_t planeStride) {
    __shared__ ushort As[3][256 * BK];   // 48 KB
    __shared__ ushort Bs[3][256 * BK];   // 48 KB
    int tid = threadIdx.x;
    int lane = tid & 63, wid = tid >> 6;          // 8 waves
    int wm = wid >> 2, wn = wid & 3;
    int l15 = lane & 15, quad = lane >> 4;
    int bm = blockIdx.x, bn = blockIdx.y;
    const int K = DMODEL;

    // staging: wave wid covers issues {2*wid, 2*wid+1} of 16 per tile (A and B)
    int e0 = wid * 2, e1 = wid * 2 + 1;
    int srow0 = e0 * 16 + (lane >> 2), srow1 = e1 * 16 + (lane >> 2);
    int scol = (lane & 3) * 8;
    const ushort* Ag0 = A + (size_t)(bm * 256 + srow0) * K + scol;
    const ushort* Ag1 = A + (size_t)(bm * 256 + srow1) * K + scol;
    const ushort* Bg0 = Bt + (size_t)(bn * 256 + srow0) * K + scol;
    const ushort* Bg1 = Bt + (size_t)(bn * 256 + srow1) * K + scol;

    f32x4 acc[8][4];
    #pragma unroll
    for (int i = 0; i < 8; i++)
        #pragma unroll
        for (int j = 0; j < 4; j++)
            acc[i][j] = (f32x4){0.f, 0.f, 0.f, 0.f};

    // prologue: stage K-tiles 0 and 1 into slots 0,1
    #pragma unroll
    for (int t = 0; t < 2; t++) {
        gl_lds16u(Ag0 + t * BK, &As[t][e0 * 512]);
        gl_lds16u(Ag1 + t * BK, &As[t][e1 * 512]);
        gl_lds16u(Bg0 + t * BK, &Bs[t][e0 * 512]);
        gl_lds16u(Bg1 + t * BK, &Bs[t][e1 * 512]);
    }
    asm volatile("s_waitcnt vmcnt(4)" ::: "memory");   // tile 0 resident, tile 1 in flight
    __builtin_amdgcn_s_barrier();

    #pragma unroll 1
    for (int c = 0; c < 32; ++c) {
        // 1. prefetch K-tile c+2 into slot (c+2)%3 (stays in flight across the barrier)
        if (c + 2 < 32) {
            int s2 = (c + 2) % 3;
            int kt2 = (c + 2) * BK;
            gl_lds16u(Ag0 + kt2, &As[s2][e0 * 512]);
            gl_lds16u(Ag1 + kt2, &As[s2][e1 * 512]);
            gl_lds16u(Bg0 + kt2, &Bs[s2][e0 * 512]);
            gl_lds16u(Bg1 + kt2, &Bs[s2][e1 * 512]);
        }
        // 2. fragments from slot c%3 (resident by induction) + MFMA
        int cs = c % 3;
        short8 af[8], bf[4];
        #pragma unroll
        for (int mi = 0; mi < 8; mi++)
            af[mi] = *(const short8*)&As[cs][(wm * 128 + mi * 16 + l15) * BK + quad * 8];
        #pragma unroll
        for (int ni = 0; ni < 4; ni++)
            bf[ni] = *(const short8*)&Bs[cs][(wn * 64 + ni * 16 + l15) * BK + quad * 8];
        #pragma unroll
        for (int mi = 0; mi < 8; mi++)
            #pragma unroll
            for (int ni = 0; ni < 4; ni++)
                acc[mi][ni] = __builtin_amdgcn_mfma_f32_16x16x32_bf16(
                    af[mi], bf[ni], acc[mi][ni], 0, 0, 0);
        // 3. counted wait + barrier: tile c+1 resident for next step; c+2 stays in flight
        if (c < 30) {
            asm volatile("s_waitcnt vmcnt(4)" ::: "memory");
            __builtin_amdgcn_s_barrier();
        } else if (c == 30) {
            asm volatile("s_waitcnt vmcnt(0)" ::: "memory");   // drain last tile (tail only)
            __builtin_amdgcn_s_barrier();
        }
    }

    #pragma unroll
    for (int mi = 0; mi < 8; mi++)
        #pragma unroll
        for (int ni = 0; ni < 4; ni++)
            #pragma unroll
            for (int r = 0; r < 4; r++) {
                int row = bm * 256 + wm * 128 + mi * 16 + quad * 4 + r;
                int col = bn * 256 + wn * 64 + ni * 16 + l15;
                outF[(size_t)(col >> 10) * planeStride + (size_t)row * 1024 + (col & 1023)]
                    = acc[mi][ni][r];
            }
}

// ---------------- causal depthwise conv(k=4) + silu (+ l2norm for q/k, q/=8) ----------------
__global__ void gdn_conv(const float* __restrict__ pre,
                         const float* __restrict__ cqw, const float* __restrict__ cqb,
                         const float* __restrict__ ckw, const float* __restrict__ ckb,
                         const float* __restrict__ cvw, const float* __restrict__ cvb,
                         float* __restrict__ qn, float* __restrict__ kn, float* __restrict__ vn) {
    int m = blockIdx.x;
    int which = blockIdx.y;        // 0:q 1:k 2:v
    int t = m & (TSEQ - 1);
    const float* cw = (which == 0) ? cqw : (which == 1) ? ckw : cvw;
    const float* cb = (which == 0) ? cqb : (which == 1) ? ckb : cvb;
    float* dst = (which == 0) ? qn : (which == 1) ? kn : vn;
    int c = threadIdx.x * 4;       // 4 consecutive channels

    float w[4][4];
    #pragma unroll
    for (int i = 0; i < 4; i++) {
        float4 t4 = ((const float4*)cw)[c + i];   // taps of channel c+i
        w[i][0] = t4.x; w[i][1] = t4.y; w[i][2] = t4.z; w[i][3] = t4.w;
    }
    float4 bias = ((const float4*)cb)[threadIdx.x];
    float y[4] = {bias.x, bias.y, bias.z, bias.w};

    const float* src = pre + (size_t)which * PLANE + (size_t)m * DMODEL + c;
    #pragma unroll
    for (int j = 0; j < 4; j++) {
        int tt = t - 3 + j;
        if (tt >= 0) {
            float4 xv = *(const float4*)(src + (long)(j - 3) * DMODEL);
            y[0] += xv.x * w[0][j];
            y[1] += xv.y * w[1][j];
            y[2] += xv.z * w[2][j];
            y[3] += xv.w * w[3][j];
        }
    }
    #pragma unroll
    for (int i = 0; i < 4; i++) y[i] = silu_f(y[i]);

    if (which < 2) {   // l2norm over 64-channel head groups (16 consecutive lanes)
        float ss = y[0]*y[0] + y[1]*y[1] + y[2]*y[2] + y[3]*y[3];
        ss += __shfl_xor(ss, 1);
        ss += __shfl_xor(ss, 2);
        ss += __shfl_xor(ss, 4);
        ss += __shfl_xor(ss, 8);
        float sc = rsqrtf(ss + 1e-6f);
        if (which == 0) sc *= 0.125f;   // q /= sqrt(d)
        #pragma unroll
        for (int i = 0; i < 4; i++) y[i] *= sc;
    }
    float4 o; o.x = y[0]; o.y = y[1]; o.z = y[2]; o.w = y[3];
    ((float4*)(dst + (size_t)m * 1024))[threadIdx.x] = o;
}

// ======================= chunked delta rule (WY / UT transform), C = 64 =======================
// MFMA version (split-bf16 hi/lo fp32 emulation). Outputs:
//   WTst[u][s] bf16; U0st[s][j] bf16; Pst = PT[u][a] fp32; Rst = RT[j][a] fp32 (transposed so
//   sstep's per-cg slice [cg*16..+15][:] is a contiguous 4KB block for linear global_load_lds).
__global__ __launch_bounds__(256) void gdn_chunk(
    const float* __restrict__ kn, const float* __restrict__ vn,
    const float* __restrict__ betaT,
    ushort* __restrict__ WTst, ushort* __restrict__ U0st,
    float* __restrict__ Pst, float* __restrict__ Rst)
{
    __shared__ ushort Khi[64 * 72], Klo[64 * 72];      // K natural [t][d]
    __shared__ ushort KThi[64 * 72], KTlo[64 * 72];    // K^T [d][t]
    __shared__ ushort XThi[128 * 72], XTlo[128 * 72];  // solved [W|U0]^T [j][t] (zero until solved)
    __shared__ ushort Mneghi[64 * 72], Mneglo[64 * 72];// -strict_lower(M), 0 elsewhere
    __shared__ float  Xf[64 * 132];                    // RHS beta[K|V], then strip-updated
    __shared__ float  MmDiag[4 * 16 * 20];             // fp32 diag 16x16 blocks of M
    __shared__ float  bet[64];

    int c = blockIdx.x, bh = blockIdx.y;
    int b = bh >> 4, h = bh & 15;
    int tid = threadIdx.x;
    int w = tid >> 6, lane = tid & 63;
    int l15 = lane & 15, quad = lane >> 4;
    size_t gbase = ((size_t)(b * TSEQ + c * 64)) * DMODEL + h * 64;
    size_t u = (size_t)bh * 32 + c;

    // ---------- phase 0: load K,V,beta; build splits; init Xf; zero XT ----------
    if (tid < 64) bet[tid] = betaT[((size_t)bh << 11) + c * 64 + tid];
    #pragma unroll
    for (int i = 0; i < 18; i++) {
        ((uint*)XThi)[tid + 256 * i] = 0u;
        ((uint*)XTlo)[tid + 256 * i] = 0u;
    }
    __syncthreads();

    #pragma unroll
    for (int i = 0; i < 4; i++) {
        int idx = tid + 256 * i;
        int r = idx >> 4, c4 = (idx & 15) * 4;
        float4 kv = *(const float4*)&kn[gbase + (size_t)r * DMODEL + c4];
        float4 vv = *(const float4*)&vn[gbase + (size_t)r * DMODEL + c4];
        float br = bet[r];
        float4 xk; xk.x = br * kv.x; xk.y = br * kv.y; xk.z = br * kv.z; xk.w = br * kv.w;
        float4 xv; xv.x = br * vv.x; xv.y = br * vv.y; xv.z = br * vv.z; xv.w = br * vv.w;
        *(float4*)&Xf[r * 132 + c4] = xk;
        *(float4*)&Xf[r * 132 + 64 + c4] = xv;
        ushort h0, l0, h1, l1, h2, l2, h3, l3;
        split2(kv.x, h0, l0); split2(kv.y, h1, l1);
        split2(kv.z, h2, l2); split2(kv.w, h3, l3);
        ((uint*)&Khi[r * 72 + c4])[0] = (uint)h0 | ((uint)h1 << 16);
        ((uint*)&Khi[r * 72 + c4])[1] = (uint)h2 | ((uint)h3 << 16);
        ((uint*)&Klo[r * 72 + c4])[0] = (uint)l0 | ((uint)l1 << 16);
        ((uint*)&Klo[r * 72 + c4])[1] = (uint)l2 | ((uint)l3 << 16);
        KThi[(c4 + 0) * 72 + r] = h0; KThi[(c4 + 1) * 72 + r] = h1;
        KThi[(c4 + 2) * 72 + r] = h2; KThi[(c4 + 3) * 72 + r] = h3;
        KTlo[(c4 + 0) * 72 + r] = l0; KTlo[(c4 + 1) * 72 + r] = l1;
        KTlo[(c4 + 2) * 72 + r] = l2; KTlo[(c4 + 3) * 72 + r] = l3;
    }
    __syncthreads();

    // ---------- phase 1: M = beta K K^T via MFMA (wave w -> rows 16w..16w+15) ----------
    {
        f32x4 mAcc[4];
        #pragma unroll
        for (int tn = 0; tn < 4; tn++) mAcc[tn] = (f32x4){0.f, 0.f, 0.f, 0.f};
        #pragma unroll
        for (int ks = 0; ks < 2; ks++) {
            short8 aH = *(const short8*)&Khi[(16 * w + l15) * 72 + ks * 32 + quad * 8];
            short8 aL = *(const short8*)&Klo[(16 * w + l15) * 72 + ks * 32 + quad * 8];
            #pragma unroll
            for (int tn = 0; tn < 4; tn++) {
                short8 bH = *(const short8*)&Khi[(16 * tn + l15) * 72 + ks * 32 + quad * 8];
                short8 bL = *(const short8*)&Klo[(16 * tn + l15) * 72 + ks * 32 + quad * 8];
                mAcc[tn] = __builtin_amdgcn_mfma_f32_16x16x32_bf16(aH, bH, mAcc[tn], 0, 0, 0);
                mAcc[tn] = __builtin_amdgcn_mfma_f32_16x16x32_bf16(aH, bL, mAcc[tn], 0, 0, 0);
                mAcc[tn] = __builtin_amdgcn_mfma_f32_16x16x32_bf16(aL, bH, mAcc[tn], 0, 0, 0);
            }
        }
        #pragma unroll
        for (int tn = 0; tn < 4; tn++) {
            #pragma unroll
            for (int r = 0; r < 4; r++) {
                int row = 16 * w + quad * 4 + r;
                int col = tn * 16 + l15;
                float val = mAcc[tn][r] * bet[row];
                ushort hh = 0, ll = 0;
                if (col < row) {
                    float nv = -val;
                    hh = f2bf(nv);
                    ll = f2bf(nv - bf2f(hh));
                }
                Mneghi[row * 72 + col] = hh;
                Mneglo[row * 72 + col] = ll;
                if (tn == w) MmDiag[w * 320 + (row & 15) * 20 + l15] = val;
            }
        }
    }
    __syncthreads();

    // ---------- phase 2: 4 strips: MFMA update + in-register triangle solve ----------
    #pragma unroll 1
    for (int st = 0; st < 4; st++) {
        int tb = st * 16;
        if (st) {
            // strip update: X_strip -= M[strip][:] * Xsolved  (Mneg = -M, XT zeros beyond solved)
            f32x4 acc2[2];
            #pragma unroll
            for (int e = 0; e < 2; e++) {
                int tn = 2 * w + e;
                #pragma unroll
                for (int r = 0; r < 4; r++)
                    acc2[e][r] = Xf[(tb + quad * 4 + r) * 132 + tn * 16 + l15];
            }
            #pragma unroll
            for (int ks = 0; ks < 2; ks++) {
                short8 aH = *(const short8*)&Mneghi[(tb + l15) * 72 + ks * 32 + quad * 8];
                short8 aL = *(const short8*)&Mneglo[(tb + l15) * 72 + ks * 32 + quad * 8];
                #pragma unroll
                for (int e = 0; e < 2; e++) {
                    int tn = 2 * w + e;
                    short8 bH = *(const short8*)&XThi[(tn * 16 + l15) * 72 + ks * 32 + quad * 8];
                    short8 bL = *(const short8*)&XTlo[(tn * 16 + l15) * 72 + ks * 32 + quad * 8];
                    acc2[e] = __builtin_amdgcn_mfma_f32_16x16x32_bf16(aH, bH, acc2[e], 0, 0, 0);
                    acc2[e] = __builtin_amdgcn_mfma_f32_16x16x32_bf16(aH, bL, acc2[e], 0, 0, 0);
                    acc2[e] = __builtin_amdgcn_mfma_f32_16x16x32_bf16(aL, bH, acc2[e], 0, 0, 0);
                }
            }
            #pragma unroll
            for (int e = 0; e < 2; e++) {
                int tn = 2 * w + e;
                #pragma unroll
                for (int r = 0; r < 4; r++)
                    Xf[(tb + quad * 4 + r) * 132 + tn * 16 + l15] = acc2[e][r];
            }
        }
        __syncthreads();

        if (tid < 128) {     // column j solver (2 waves)
            const int j = tid;
            const float* MD = &MmDiag[st * 320];   // [16][20]
            float xr[16];
            #pragma unroll
            for (int sb = 0; sb < 4; sb++) {
                float b4[4];
                #pragma unroll
                for (int i = 0; i < 4; i++)
                    b4[i] = Xf[(tb + sb * 4 + i) * 132 + j];
                #pragma unroll
                for (int u4 = 0; u4 < sb; u4++) {
                    #pragma unroll
                    for (int i = 0; i < 4; i++) {
                        float4 m4 = *(const float4*)&MD[(sb * 4 + i) * 20 + u4 * 4];
                        b4[i] -= m4.x * xr[u4 * 4 + 0] + m4.y * xr[u4 * 4 + 1]
                               + m4.z * xr[u4 * 4 + 2] + m4.w * xr[u4 * 4 + 3];
                    }
                }
                float x0 = b4[0];
                float x1 = b4[1] - MD[(sb * 4 + 1) * 20 + sb * 4 + 0] * x0;
                float x2 = b4[2] - MD[(sb * 4 + 2) * 20 + sb * 4 + 0] * x0
                                 - MD[(sb * 4 + 2) * 20 + sb * 4 + 1] * x1;
                float x3 = b4[3] - MD[(sb * 4 + 3) * 20 + sb * 4 + 0] * x0
                                 - MD[(sb * 4 + 3) * 20 + sb * 4 + 1] * x1
                                 - MD[(sb * 4 + 3) * 20 + sb * 4 + 2] * x2;
                xr[sb * 4 + 0] = x0; xr[sb * 4 + 1] = x1;
                xr[sb * 4 + 2] = x2; xr[sb * 4 + 3] = x3;
            }
            // split + store to XT (hi/lo) and global W/U0 (hi = bf16 value)
            ushort hs[16], ls[16];
            #pragma unroll
            for (int i = 0; i < 16; i++) split2(xr[i], hs[i], ls[i]);
            uint4 ph0, ph1, pl0, pl1;
            ph0.x = (uint)hs[0] | ((uint)hs[1] << 16);  ph0.y = (uint)hs[2] | ((uint)hs[3] << 16);
            ph0.z = (uint)hs[4] | ((uint)hs[5] << 16);  ph0.w = (uint)hs[6] | ((uint)hs[7] << 16);
            ph1.x = (uint)hs[8] | ((uint)hs[9] << 16);  ph1.y = (uint)hs[10] | ((uint)hs[11] << 16);
            ph1.z = (uint)hs[12] | ((uint)hs[13] << 16); ph1.w = (uint)hs[14] | ((uint)hs[15] << 16);
            pl0.x = (uint)ls[0] | ((uint)ls[1] << 16);  pl0.y = (uint)ls[2] | ((uint)ls[3] << 16);
            pl0.z = (uint)ls[4] | ((uint)ls[5] << 16);  pl0.w = (uint)ls[6] | ((uint)ls[7] << 16);
            pl1.x = (uint)ls[8] | ((uint)ls[9] << 16);  pl1.y = (uint)ls[10] | ((uint)ls[11] << 16);
            pl1.z = (uint)ls[12] | ((uint)ls[13] << 16); pl1.w = (uint)ls[14] | ((uint)ls[15] << 16);
            *(uint4*)&XThi[j * 72 + tb] = ph0;  *(uint4*)&XThi[j * 72 + tb + 8] = ph1;
            *(uint4*)&XTlo[j * 72 + tb] = pl0;  *(uint4*)&XTlo[j * 72 + tb + 8] = pl1;
            if (j < 64) {   // W^T[u=j][s=tb..tb+15]
                ushort* wdst = WTst + u * 4096 + j * 64 + tb;
                *(uint4*)wdst = ph0; *(uint4*)(wdst + 8) = ph1;
            } else {        // U0[s=tb+i][jv=j-64]
                ushort* udst = U0st + u * 4096 + (size_t)tb * 64 + (j - 64);
                #pragma unroll
                for (int i = 0; i < 16; i++) udst[i * 64] = hs[i];
            }
        }
        __syncthreads();
    }

    // ---------- phase 3: P^T = W^T K  and  R = K^T U0 via MFMA ----------
    {
        f32x4 pAcc[4], rAcc[4];
        #pragma unroll
        for (int tn = 0; tn < 4; tn++) {
            pAcc[tn] = (f32x4){0.f, 0.f, 0.f, 0.f};
            rAcc[tn] = (f32x4){0.f, 0.f, 0.f, 0.f};
        }
        #pragma unroll
        for (int ks = 0; ks < 2; ks++) {
            short8 aH = *(const short8*)&XThi[(16 * w + l15) * 72 + ks * 32 + quad * 8]; // W^T rows
            short8 aL = *(const short8*)&XTlo[(16 * w + l15) * 72 + ks * 32 + quad * 8];
            short8 cH = *(const short8*)&KThi[(16 * w + l15) * 72 + ks * 32 + quad * 8]; // K^T rows
            short8 cL = *(const short8*)&KTlo[(16 * w + l15) * 72 + ks * 32 + quad * 8];
            #pragma unroll
            for (int tn = 0; tn < 4; tn++) {
                short8 bH = *(const short8*)&KThi[(16 * tn + l15) * 72 + ks * 32 + quad * 8];
                short8 bL = *(const short8*)&KTlo[(16 * tn + l15) * 72 + ks * 32 + quad * 8];
                pAcc[tn] = __builtin_amdgcn_mfma_f32_16x16x32_bf16(aH, bH, pAcc[tn], 0, 0, 0);
                pAcc[tn] = __builtin_amdgcn_mfma_f32_16x16x32_bf16(aH, bL, pAcc[tn], 0, 0, 0);
                pAcc[tn] = __builtin_amdgcn_mfma_f32_16x16x32_bf16(aL, bH, pAcc[tn], 0, 0, 0);
                short8 uH = *(const short8*)&XThi[(64 + 16 * tn + l15) * 72 + ks * 32 + quad * 8];
                short8 uL = *(const short8*)&XTlo[(64 + 16 * tn + l15) * 72 + ks * 32 + quad * 8];
                rAcc[tn] = __builtin_amdgcn_mfma_f32_16x16x32_bf16(cH, uH, rAcc[tn], 0, 0, 0);
                rAcc[tn] = __builtin_amdgcn_mfma_f32_16x16x32_bf16(cH, uL, rAcc[tn], 0, 0, 0);
                rAcc[tn] = __builtin_amdgcn_mfma_f32_16x16x32_bf16(cL, uH, rAcc[tn], 0, 0, 0);
            }
        }
        float* Po = Pst + u * 4096;
        float* Ro = Rst + u * 4096;
        #pragma unroll
        for (int tn = 0; tn < 4; tn++) {
            #pragma unroll
            for (int r = 0; r < 4; r++) {
                int row = 16 * w + quad * 4 + r;
                int col = tn * 16 + l15;
                Po[row * 64 + col] = pAcc[tn][r];   // PT[u][a]
                Ro[col * 64 + row] = rAcc[tn][r];   // RT[j][a]  (transposed for sstep slicing)
            }
        }
    }
}

// serial cross-chunk state propagation: S <- S - P*S + R ; records S0 per chunk.
// grid 128 = (bh, 4 col-groups of 16 v-cols). Software-pipelined: PT and RT slices are
// triple-buffered in LDS with depth-2 global_load_lds prefetch; barriers use counted
// s_waitcnt vmcnt(N) (never 0 in steady state) so prefetch loads stay in flight across
// barriers. S held transposed double-buffered in LDS -> one barrier per step.
__global__ __launch_bounds__(256) void gdn_sstep(const float* __restrict__ Pst,
                                                 const float* __restrict__ Rst,
                                                 float* __restrict__ S0st)
{
    __shared__ float PTl[3][4096];      // PT[u][a] per chunk
    __shared__ float Rl[3][1024];       // RT slice [16 j][64 a]
    __shared__ float SshT[2][16][72];   // S^T: SshT[j][a] = S[a][j]

    int bh = blockIdx.x >> 2, cg = blockIdx.x & 3;
    int tid = threadIdx.x;
    int t0 = (tid & 15) * 4;            // a-rows owned (4)
    int j  = tid >> 4;                  // local v-col 0..15
    int jg = cg * 16 + j;
    int wv = tid >> 6, ln = tid & 63;

    size_t ubase = (size_t)bh * 32 * 4096;

    // zero S buffer 0 (each thread owns SshT[0][j][t0..t0+3])
    *(float4*)&SshT[0][j][t0] = (float4){0.f, 0.f, 0.f, 0.f};

    // prologue: issue chunks 0 and 1
    #pragma unroll
    for (int t = 0; t < 2; t++) {
        size_t ub = ubase + (size_t)t * 4096;
        #pragma unroll
        for (int q = 0; q < 4; q++)
            gl_lds16(Pst + ub + (wv * 4 + q) * 256 + ln * 4, &PTl[t][(wv * 4 + q) * 256]);
        gl_lds16(Rst + ub + cg * 1024 + wv * 256 + ln * 4, &Rl[t][wv * 256]);
    }
    asm volatile("s_waitcnt vmcnt(5)" ::: "memory");   // chunk 0 resident (chunk 1 in flight)
    asm volatile("s_waitcnt lgkmcnt(0)" ::: "memory");
    __builtin_amdgcn_s_barrier();

    int cur3 = 0;
    #pragma unroll 1
    for (int c = 0; c < 32; ++c) {
        int cur = c & 1, nxt = cur ^ 1;
        // 1. prefetch chunk c+2 into buffer (cur3+2)%3
        if (c + 2 < 32) {
            int b3 = cur3 + 2; if (b3 >= 3) b3 -= 3;
            size_t ub2 = ubase + (size_t)(c + 2) * 4096;
            #pragma unroll
            for (int q = 0; q < 4; q++)
                gl_lds16(Pst + ub2 + (wv * 4 + q) * 256 + ln * 4, &PTl[b3][(wv * 4 + q) * 256]);
            gl_lds16(Rst + ub2 + cg * 1024 + wv * 256 + ln * 4, &Rl[b3][wv * 256]);
        }
        // 2. sold, S0 store (off critical path), acc init
        float4 sold = *(const float4*)&SshT[cur][j][t0];
        size_t ub = ubase + (size_t)c * 4096;
        S0st[ub + (size_t)(t0 + 0) * 64 + jg] = sold.x;
        S0st[ub + (size_t)(t0 + 1) * 64 + jg] = sold.y;
        S0st[ub + (size_t)(t0 + 2) * 64 + jg] = sold.z;
        S0st[ub + (size_t)(t0 + 3) * 64 + jg] = sold.w;
        float4 racc = *(const float4*)&Rl[cur3][j * 64 + t0];
        // 3. sub = P[t0..t0+3][:] . S[:][j]
        float sub0 = 0.f, sub1 = 0.f, sub2 = 0.f, sub3 = 0.f;
        #pragma unroll
        for (int u4 = 0; u4 < 16; u4++) {
            float4 sv = *(const float4*)&SshT[cur][j][u4 * 4];
            #pragma unroll
            for (int e = 0; e < 4; e++) {
                float4 pt = *(const float4*)&PTl[cur3][(u4 * 4 + e) * 64 + t0];
                float s1 = (e == 0) ? sv.x : (e == 1) ? sv.y : (e == 2) ? sv.z : sv.w;
                sub0 = fmaf(pt.x, s1, sub0);
                sub1 = fmaf(pt.y, s1, sub1);
                sub2 = fmaf(pt.z, s1, sub2);
                sub3 = fmaf(pt.w, s1, sub3);
            }
        }
        // 4. write S_new into the other S buffer
        float4 snew;
        snew.x = sold.x + racc.x - sub0;
        snew.y = sold.y + racc.y - sub1;
        snew.z = sold.z + racc.z - sub2;
        snew.w = sold.w + racc.w - sub3;
        *(float4*)&SshT[nxt][j][t0] = snew;
        // 5. counted waits + barrier (keeps prefetches in flight)
        if (c == 0)       { asm volatile("s_waitcnt vmcnt(9)"  ::: "memory"); }
        else if (c < 30)  { asm volatile("s_waitcnt vmcnt(13)" ::: "memory"); }
        else if (c == 30) { asm volatile("s_waitcnt vmcnt(8)"  ::: "memory"); }
        asm volatile("s_waitcnt lgkmcnt(0)" ::: "memory");
        __builtin_amdgcn_s_barrier();
        cur3 += 1; if (cur3 >= 3) cur3 -= 3;
    }
}

// output pass (MFMA, split-bf16): O = Q S0 + tril_incl(Q K^T) (U0 - W S0)
__global__ __launch_bounds__(256) void gdn_opass(
    const float* __restrict__ qn, const float* __restrict__ kn,
    const float* __restrict__ S0st, const ushort* __restrict__ WTst,
    const ushort* __restrict__ U0st, float* __restrict__ otmp2)
{
    __shared__ ushort pool[36864];          // 73728 B
    ushort* Qhi  = pool;                    // [t][d] pitch 72
    ushort* Qlo  = pool + 4608;
    ushort* Khi  = pool + 2 * 4608;         // [s][d]
    ushort* Klo  = pool + 3 * 4608;
    ushort* SThi = pool + 4 * 4608;         // S0^T [jv][a]
    ushort* STlo = pool + 5 * 4608;
    ushort* Wn   = pool + 6 * 4608;         // -W [s][u]
    ushort* Uu   = pool + 7 * 4608;         // U0 [s][jv] pitch 64
    ushort* Ghi  = Qhi;  ushort* Glo  = Qlo;   // overlay: masked G [t][s]
    ushort* EThi = Khi;  ushort* ETlo = Klo;   // overlay: E^T [jv][s]

    int c = blockIdx.x, bh = blockIdx.y;
    int b = bh >> 4, h = bh & 15;
    int tid = threadIdx.x;
    int w = tid >> 6, lane = tid & 63;
    int l15 = lane & 15, quad = lane >> 4;
    size_t gbase = ((size_t)(b * TSEQ + c * 64)) * DMODEL + h * 64;
    size_t u = (size_t)bh * 32 + c;

    // ---- load & split Q,K (natural); S0 (transpose+split); -W; U0 ----
    #pragma unroll
    for (int i = 0; i < 4; i++) {
        int idx = tid + 256 * i;
        int r = idx >> 4, c4 = (idx & 15) * 4;
        float4 qv = *(const float4*)&qn[gbase + (size_t)r * DMODEL + c4];
        float4 kv = *(const float4*)&kn[gbase + (size_t)r * DMODEL + c4];
        float4 sv = *(const float4*)&S0st[u * 4096 + (size_t)idx * 4];
        ushort h0, l0, h1, l1, h2, l2, h3, l3;
        split2(qv.x, h0, l0); split2(qv.y, h1, l1);
        split2(qv.z, h2, l2); split2(qv.w, h3, l3);
        ((uint*)&Qhi[r * 72 + c4])[0] = (uint)h0 | ((uint)h1 << 16);
        ((uint*)&Qhi[r * 72 + c4])[1] = (uint)h2 | ((uint)h3 << 16);
        ((uint*)&Qlo[r * 72 + c4])[0] = (uint)l0 | ((uint)l1 << 16);
        ((uint*)&Qlo[r * 72 + c4])[1] = (uint)l2 | ((uint)l3 << 16);
        split2(kv.x, h0, l0); split2(kv.y, h1, l1);
        split2(kv.z, h2, l2); split2(kv.w, h3, l3);
        ((uint*)&Khi[r * 72 + c4])[0] = (uint)h0 | ((uint)h1 << 16);
        ((uint*)&Khi[r * 72 + c4])[1] = (uint)h2 | ((uint)h3 << 16);
        ((uint*)&Klo[r * 72 + c4])[0] = (uint)l0 | ((uint)l1 << 16);
        ((uint*)&Klo[r * 72 + c4])[1] = (uint)l2 | ((uint)l3 << 16);
        split2(sv.x, h0, l0); split2(sv.y, h1, l1);
        split2(sv.z, h2, l2); split2(sv.w, h3, l3);
        SThi[(c4 + 0) * 72 + r] = h0; STlo[(c4 + 0) * 72 + r] = l0;
        SThi[(c4 + 1) * 72 + r] = h1; STlo[(c4 + 1) * 72 + r] = l1;
        SThi[(c4 + 2) * 72 + r] = h2; STlo[(c4 + 2) * 72 + r] = l2;
        SThi[(c4 + 3) * 72 + r] = h3; STlo[(c4 + 3) * 72 + r] = l3;
    }
    #pragma unroll
    for (int i = 0; i < 2; i++) {
        int idx = tid + 256 * i;
        uint4 w8 = ((const uint4*)(WTst + u * 4096))[idx];    // WT[u][s], 8 along s
        int ur = idx >> 3, t8 = (idx & 7) * 8;
        uint v0 = w8.x ^ 0x80008000u, v1 = w8.y ^ 0x80008000u;
        uint v2 = w8.z ^ 0x80008000u, v3 = w8.w ^ 0x80008000u;
        Wn[(t8 + 0) * 72 + ur] = (ushort)v0; Wn[(t8 + 1) * 72 + ur] = (ushort)(v0 >> 16);
        Wn[(t8 + 2) * 72 + ur] = (ushort)v1; Wn[(t8 + 3) * 72 + ur] = (ushort)(v1 >> 16);
        Wn[(t8 + 4) * 72 + ur] = (ushort)v2; Wn[(t8 + 5) * 72 + ur] = (ushort)(v2 >> 16);
        Wn[(t8 + 6) * 72 + ur] = (ushort)v3; Wn[(t8 + 7) * 72 + ur] = (ushort)(v3 >> 16);
        ((uint4*)Uu)[idx] = ((const uint4*)(U0st + u * 4096))[idx];
    }
    __syncthreads();

    // ---- set 1: G = Q K^T ; O1 = Q S0 ; E = U0 - W S0 (acc init U0, W negated) ----
    f32x4 accG[4], accO[4], accE[4];
    #pragma unroll
    for (int tn = 0; tn < 4; tn++) {
        accG[tn] = (f32x4){0.f, 0.f, 0.f, 0.f};
        accO[tn] = (f32x4){0.f, 0.f, 0.f, 0.f};
        #pragma unroll
        for (int r = 0; r < 4; r++)
            accE[tn][r] = bf2f(Uu[(16 * w + quad * 4 + r) * 64 + tn * 16 + l15]);
    }
    #pragma unroll
    for (int ks = 0; ks < 2; ks++) {
        int ko = ks * 32 + quad * 8;
        short8 qH = *(const short8*)&Qhi[(16 * w + l15) * 72 + ko];
        short8 qL = *(const short8*)&Qlo[(16 * w + l15) * 72 + ko];
        short8 wA = *(const short8*)&Wn [(16 * w + l15) * 72 + ko];
        #pragma unroll
        for (int tn = 0; tn < 4; tn++) {
            short8 kH = *(const short8*)&Khi [(16 * tn + l15) * 72 + ko];
            short8 kL = *(const short8*)&Klo [(16 * tn + l15) * 72 + ko];
            short8 sH = *(const short8*)&SThi[(16 * tn + l15) * 72 + ko];
            short8 sL = *(const short8*)&STlo[(16 * tn + l15) * 72 + ko];
            accG[tn] = __builtin_amdgcn_mfma_f32_16x16x32_bf16(qH, kH, accG[tn], 0, 0, 0);
            accG[tn] = __builtin_amdgcn_mfma_f32_16x16x32_bf16(qH, kL, accG[tn], 0, 0, 0);
            accG[tn] = __builtin_amdgcn_mfma_f32_16x16x32_bf16(qL, kH, accG[tn], 0, 0, 0);
            accO[tn] = __builtin_amdgcn_mfma_f32_16x16x32_bf16(qH, sH, accO[tn], 0, 0, 0);
            accO[tn] = __builtin_amdgcn_mfma_f32_16x16x32_bf16(qH, sL, accO[tn], 0, 0, 0);
            accO[tn] = __builtin_amdgcn_mfma_f32_16x16x32_bf16(qL, sH, accO[tn], 0, 0, 0);
            accE[tn] = __builtin_amdgcn_mfma_f32_16x16x32_bf16(wA, sH, accE[tn], 0, 0, 0);
            accE[tn] = __builtin_amdgcn_mfma_f32_16x16x32_bf16(wA, sL, accE[tn], 0, 0, 0);
        }
    }
    __syncthreads();   // all set-1 LDS reads complete before overlay writes

    // ---- write masked G (split) and E^T (split) into overlay buffers ----
    #pragma unroll
    for (int tn = 0; tn < 4; tn++) {
        #pragma unroll
        for (int r = 0; r < 4; r++) {
            int row = 16 * w + quad * 4 + r;
            int col = tn * 16 + l15;
            float gv = (col <= row) ? accG[tn][r] : 0.f;
            ushort gh, gl; split2(gv, gh, gl);
            Ghi[row * 72 + col] = gh; Glo[row * 72 + col] = gl;
            ushort eh, el; split2(accE[tn][r], eh, el);
            EThi[col * 72 + row] = eh; ETlo[col * 72 + row] = el;
        }
    }
    __syncthreads();

    // ---- set 2: O += G E ----
    #pragma unroll
    for (int ks = 0; ks < 2; ks++) {
        int ko = ks * 32 + quad * 8;
        short8 gH = *(const short8*)&Ghi[(16 * w + l15) * 72 + ko];
        short8 gL = *(const short8*)&Glo[(16 * w + l15) * 72 + ko];
        #pragma unroll
        for (int tn = 0; tn < 4; tn++) {
            short8 eH = *(const short8*)&EThi[(16 * tn + l15) * 72 + ko];
            short8 eL = *(const short8*)&ETlo[(16 * tn + l15) * 72 + ko];
            accO[tn] = __builtin_amdgcn_mfma_f32_16x16x32_bf16(gH, eH, accO[tn], 0, 0, 0);
            accO[tn] = __builtin_amdgcn_mfma_f32_16x16x32_bf16(gH, eL, accO[tn], 0, 0, 0);
            accO[tn] = __builtin_amdgcn_mfma_f32_16x16x32_bf16(gL, eH, accO[tn], 0, 0, 0);
        }
    }

    // ---- epilogue ----
    #pragma unroll
    for (int tn = 0; tn < 4; tn++) {
        #pragma unroll
        for (int r = 0; r < 4; r++) {
            int row = 16 * w + quad * 4 + r;
            int col = tn * 16 + l15;
            otmp2[(((size_t)bh * 16 + (col >> 2)) * TSEQ + c * 64 + row) * 4 + (col & 3)]
                = accO[tn][r];
        }
    }
}

// ---------------- RMSNorm * nw * silu(gate) -> bf16 ----------------
__global__ void gdn_fuse(const float* __restrict__ otmp2, const float* __restrict__ pre,
                         const float* __restrict__ nw, ushort* __restrict__ ofused) {
    int m = blockIdx.x;
    int b = m >> 11, t = m & (TSEQ - 1);
    int tid = threadIdx.x;
    float4 o = ((const float4*)otmp2)[((size_t)((b * NH + (tid >> 4)) * 16 + (tid & 15))) * TSEQ + t];
    float ss = o.x*o.x + o.y*o.y + o.z*o.z + o.w*o.w;
    ss += __shfl_xor(ss, 1);
    ss += __shfl_xor(ss, 2);
    ss += __shfl_xor(ss, 4);
    ss += __shfl_xor(ss, 8);
    float r = rsqrtf(ss * (1.f / 64.f) + 1e-5f);
    float4 nwv = ((const float4*)nw)[tid & 15];
    float4 g = ((const float4*)(pre + 3 * (size_t)PLANE + (size_t)m * DMODEL))[tid];
    ushort4 out;
    out.x = f2bf(o.x * r * nwv.x * silu_f(g.x));
    out.y = f2bf(o.y * r * nwv.y * silu_f(g.y));
    out.z = f2bf(o.z * r * nwv.z * silu_f(g.z));
    out.w = f2bf(o.w * r * nwv.w * silu_f(g.w));
    ((ushort4*)ofused)[m * 256 + tid] = out;
}

extern "C" void kernel_launch(void* const* d_in, const int* in_sizes, int n_in,
                              void* d_out, int out_size, void* d_ws, size_t ws_size,
                              hipStream_t stream) {
    const float* x    = (const float*)d_in[0];
    const float* Wq   = (const float*)d_in[1];
    const float* Wk   = (const float*)d_in[2];
    const float* Wv   = (const float*)d_in[3];
    const float* Wo   = (const float*)d_in[4];
    const float* Wg   = (const float*)d_in[5];
    const float* Wb   = (const float*)d_in[6];
    const float* cq_w = (const float*)d_in[7];
    const float* cq_b = (const float*)d_in[8];
    const float* ck_w = (const float*)d_in[9];
    const float* ck_b = (const float*)d_in[10];
    const float* cv_w = (const float*)d_in[11];
    const float* cv_b = (const float*)d_in[12];
    const float* nw   = (const float*)d_in[13];

    char* ws = (char*)d_ws;
    ushort* xb     = (ushort*)(ws);                       // 8 MB; reused as WT bf16 after GEMM
    ushort* wt     = (ushort*)(ws + 8388608);             // 10 MB (5 transposed bf16 weights)
    float*  pre    = (float*)(ws + 18874368);             // 64 MB: 4 planes [4096][1024] q|k|v|g
    float*  qn     = (float*)(ws + 85983232);             // 16 MB
    float*  kn     = (float*)(ws + 102760448);            // 16 MB
    float*  vn     = (float*)(ws + 119537664);            // 16 MB
    float*  betaT  = (float*)(ws + 136314880);            // 256 KB
    float*  otmp2  = (float*)(ws + 136577024);            // 16 MB
    ushort* ofused = (ushort*)(ws + 153354240);           // 8 MB; doubles as U0 bf16 earlier

    // dead-region reuse (all safely ordered by stream):
    float*  Pst  = pre;               // q-plane, dead after conv
    float*  Rst  = pre + PLANE;       // k-plane, dead after conv
    float*  S0st = pre + 2 * PLANE;   // v-plane, dead after conv
    ushort* WTst = xb;                // dead after pre-GEMM
    ushort* U0st = ofused;            // written later by fuse (after opass consumes it)

    // 1. x -> bf16
    gdn_cvt_x<<<4096, 256, 0, stream>>>(x, xb);
    // 2. transpose+convert 5 weights
    gdn_cvt_w<<<dim3(32, 32, 5), dim3(32, 8), 0, stream>>>(Wq, Wk, Wv, Wg, Wo, wt);
    // 3. betaT (fp32 exact)
    gdn_beta<<<256, 256, 0, stream>>>(x, Wb, betaT);
    // 4. fused q/k/v/g pre-activation GEMM -> 4 planes (256^2 counted-vmcnt pipeline)
    gdn_gemm256<<<dim3(16, 16), 512, 0, stream>>>(xb, wt, pre, (size_t)PLANE);
    // 5. conv + silu (+ l2norm)
    gdn_conv<<<dim3(4096, 3), 256, 0, stream>>>(pre, cq_w, cq_b, ck_w, ck_b, cv_w, cv_b,
                                                qn, kn, vn);
    // 6a. chunk-parallel precompute (M solve, W/U0, P/R) — MFMA split-bf16
    gdn_chunk<<<dim3(32, 32), 256, 0, stream>>>(kn, vn, betaT, WTst, U0st, Pst, Rst);
    // 6b. serial state propagation (32 chunk steps, counted-vmcnt pipeline)
    gdn_sstep<<<128, 256, 0, stream>>>(Pst, Rst, S0st);
    // 6c. chunk-parallel outputs (MFMA split-bf16)
    gdn_opass<<<dim3(32, 32), 256, 0, stream>>>(qn, kn, S0st, WTst, U0st, otmp2);
    // 7. RMSNorm * nw * silu(gate) -> bf16
    gdn_fuse<<<4096, 256, 0, stream>>>(otmp2, pre, nw, ofused);
    // 8. final GEMM -> d_out (fp32 output), 128^2 (N=1024 -> 256 blocks)
    gdn_gemm<<<dim3(32, 8), 256, 0, stream>>>(ofused, wt + 4 * 1024 * 1024,
                                              (float*)d_out, (size_t)0);
}

// Round 7
// 375.479 us; speedup vs baseline: 1.0473x; 1.0473x over previous
//
#include <hip/hip_runtime.h>
#include <hip/hip_bf16.h>

typedef __attribute__((ext_vector_type(8))) short short8;
typedef __attribute__((ext_vector_type(4))) float f32x4;

#define TSEQ 2048
#define DMODEL 1024
#define NH 16
#define HD 64
#define PLANE 4194304   // floats per [4096][1024] plane

__device__ __forceinline__ ushort f2bf(float f) {
    union { float f; unsigned int u; } c; c.f = f;
    unsigned int u = c.u + 0x7fffu + ((c.u >> 16) & 1u);   // RNE
    return (ushort)(u >> 16);
}

__device__ __forceinline__ float bf2f(ushort u) {
    union { unsigned int i; float f; } c; c.i = ((unsigned int)u) << 16;
    return c.f;
}

// split fp32 into hi+lo bf16 (pair reproduces x to ~2^-17 relative)
__device__ __forceinline__ void split2(float x, ushort& h, ushort& l) {
    h = f2bf(x);
    float r = x - bf2f(h);
    l = f2bf(r);
}

__device__ __forceinline__ float silu_f(float y) {
    return y / (1.f + __expf(-y));
}

// async global->LDS (dest = wave-uniform base + lane*16)
__device__ __forceinline__ void gl_lds16(const float* g, float* l) {
    __builtin_amdgcn_global_load_lds(
        (__attribute__((address_space(1))) void*)g,
        (__attribute__((address_space(3))) void*)l, 16, 0, 0);
}
__device__ __forceinline__ void gl_lds16u(const ushort* g, ushort* l) {
    __builtin_amdgcn_global_load_lds(
        (__attribute__((address_space(1))) void*)g,
        (__attribute__((address_space(3))) void*)l, 16, 0, 0);
}

// ---------------- convert x -> bf16 ----------------
__global__ void gdn_cvt_x(const float* __restrict__ x, ushort* __restrict__ xb) {
    int i = blockIdx.x * 256 + threadIdx.x;           // one float4 per thread
    float4 v = ((const float4*)x)[i];
    ushort4 o;
    o.x = f2bf(v.x); o.y = f2bf(v.y); o.z = f2bf(v.z); o.w = f2bf(v.w);
    ((ushort4*)xb)[i] = o;
}

// ------------- transpose+convert weights: W[k][n] f32 -> wt[z][n][k] bf16 -------------
__global__ void gdn_cvt_w(const float* __restrict__ Wq, const float* __restrict__ Wk,
                          const float* __restrict__ Wv, const float* __restrict__ Wg,
                          const float* __restrict__ Wo, ushort* __restrict__ wt) {
    __shared__ float tile[32][33];
    int z = blockIdx.z;
    const float* W = (z == 0) ? Wq : (z == 1) ? Wk : (z == 2) ? Wv : (z == 3) ? Wg : Wo;
    int n0 = blockIdx.x * 32, k0 = blockIdx.y * 32;
    int tx = threadIdx.x, ty = threadIdx.y;           // (32, 8)
    #pragma unroll
    for (int j = 0; j < 32; j += 8)
        tile[ty + j][tx] = W[(size_t)(k0 + ty + j) * DMODEL + n0 + tx];
    __syncthreads();
    ushort* o = wt + (size_t)z * DMODEL * DMODEL;
    #pragma unroll
    for (int j = 0; j < 32; j += 8)
        o[(size_t)(n0 + ty + j) * DMODEL + k0 + tx] = f2bf(tile[tx][ty + j]);
}

// ---------------- betaT[(b*NH+h)*TSEQ + t] = sigmoid(x @ Wb), fp32 exact ----------------
__global__ void gdn_beta(const float* __restrict__ x, const float* __restrict__ Wb,
                         float* __restrict__ betaT) {
    __shared__ float xs[16][DMODEL];
    int tid = threadIdx.x;
    int m0 = blockIdx.x * 16;
    #pragma unroll
    for (int i = 0; i < 16; i++) {
        int idx = i * 256 + tid;                 // float4 index
        int row = idx >> 8, c4 = idx & 255;
        *(float4*)&xs[row][c4 * 4] =
            *(const float4*)&x[(size_t)(m0 + row) * DMODEL + c4 * 4];
    }
    __syncthreads();
    int h = tid & 15, mi = tid >> 4;
    float acc = 0.f;
    for (int k = 0; k < DMODEL; ++k)
        acc += xs[mi][k] * Wb[k * NH + h];
    int m = m0 + mi;
    int b = m >> 11, t = m & (TSEQ - 1);
    betaT[((b * NH + h) << 11) + t] = 1.f / (1.f + __expf(-acc));
}

// ---------------- bf16 MFMA GEMM (m97 structure, 128^2): used for the final GEMM ----------
#define BK 32
__global__ __launch_bounds__(256) void gdn_gemm(const ushort* __restrict__ A,
                                                const ushort* __restrict__ Bt,
                                                float* __restrict__ outF,
                                                size_t planeStride) {
    __shared__ ushort As[128 * BK];    // 8 KB, linear
    __shared__ ushort Bs[128 * BK];    // 8 KB, linear
    int tid = threadIdx.x;
    int lane = tid & 63, wid = tid >> 6;
    int wm = wid & 1, wn = wid >> 1;
    int l15 = lane & 15, quad = lane >> 4;
    int bm = blockIdx.x, bn = blockIdx.y;
    const int K = DMODEL;

    int e0 = wid, e1 = wid + 4;
    int srow0 = e0 * 16 + (lane >> 2), srow1 = e1 * 16 + (lane >> 2);
    int scol = (lane & 3) * 8;
    const ushort* Ag0 = A + (size_t)(bm * 128 + srow0) * K + scol;
    const ushort* Ag1 = A + (size_t)(bm * 128 + srow1) * K + scol;
    const ushort* Bg0 = Bt + (size_t)(bn * 128 + srow0) * K + scol;
    const ushort* Bg1 = Bt + (size_t)(bn * 128 + srow1) * K + scol;
    ushort* Al0 = As + e0 * 512;
    ushort* Al1 = As + e1 * 512;
    ushort* Bl0 = Bs + e0 * 512;
    ushort* Bl1 = Bs + e1 * 512;

    f32x4 acc[4][4];
    #pragma unroll
    for (int i = 0; i < 4; i++)
        #pragma unroll
        for (int j = 0; j < 4; j++)
            acc[i][j] = (f32x4){0.f, 0.f, 0.f, 0.f};

    for (int kt = 0; kt < K; kt += BK) {
        __syncthreads();
        gl_lds16u(Ag0 + kt, Al0);
        gl_lds16u(Ag1 + kt, Al1);
        gl_lds16u(Bg0 + kt, Bl0);
        gl_lds16u(Bg1 + kt, Bl1);
        __syncthreads();
        short8 af[4], bf[4];
        #pragma unroll
        for (int i = 0; i < 4; i++) {
            af[i] = *(const short8*)&As[(wm * 64 + i * 16 + l15) * BK + quad * 8];
            bf[i] = *(const short8*)&Bs[(wn * 64 + i * 16 + l15) * BK + quad * 8];
        }
        #pragma unroll
        for (int mt = 0; mt < 4; mt++)
            #pragma unroll
            for (int nt = 0; nt < 4; nt++)
                acc[mt][nt] = __builtin_amdgcn_mfma_f32_16x16x32_bf16(
                    af[mt], bf[nt], acc[mt][nt], 0, 0, 0);
    }

    #pragma unroll
    for (int mt = 0; mt < 4; mt++)
        #pragma unroll
        for (int nt = 0; nt < 4; nt++)
            #pragma unroll
            for (int r = 0; r < 4; r++) {
                int row = bm * 128 + wm * 64 + mt * 16 + quad * 4 + r;
                int col = bn * 128 + wn * 64 + nt * 16 + l15;
                outF[(size_t)(col >> 10) * planeStride + (size_t)row * 1024 + (col & 1023)]
                    = acc[mt][nt][r];
            }
}

// ------------- 256^2 GEMM, triple-buffered counted-vmcnt pipeline (big GEMM) -------------
__global__ __launch_bounds__(512, 2) void gdn_gemm256(const ushort* __restrict__ A,
                                                      const ushort* __restrict__ Bt,
                                                      float* __restrict__ outF,
                                                      size_t planeStride) {
    __shared__ ushort As[3][256 * BK];   // 48 KB
    __shared__ ushort Bs[3][256 * BK];   // 48 KB
    int tid = threadIdx.x;
    int lane = tid & 63, wid = tid >> 6;          // 8 waves
    int wm = wid >> 2, wn = wid & 3;
    int l15 = lane & 15, quad = lane >> 4;
    int bm = blockIdx.x, bn = blockIdx.y;
    const int K = DMODEL;

    int e0 = wid * 2, e1 = wid * 2 + 1;
    int srow0 = e0 * 16 + (lane >> 2), srow1 = e1 * 16 + (lane >> 2);
    int scol = (lane & 3) * 8;
    const ushort* Ag0 = A + (size_t)(bm * 256 + srow0) * K + scol;
    const ushort* Ag1 = A + (size_t)(bm * 256 + srow1) * K + scol;
    const ushort* Bg0 = Bt + (size_t)(bn * 256 + srow0) * K + scol;
    const ushort* Bg1 = Bt + (size_t)(bn * 256 + srow1) * K + scol;

    f32x4 acc[8][4];
    #pragma unroll
    for (int i = 0; i < 8; i++)
        #pragma unroll
        for (int j = 0; j < 4; j++)
            acc[i][j] = (f32x4){0.f, 0.f, 0.f, 0.f};

    #pragma unroll
    for (int t = 0; t < 2; t++) {
        gl_lds16u(Ag0 + t * BK, &As[t][e0 * 512]);
        gl_lds16u(Ag1 + t * BK, &As[t][e1 * 512]);
        gl_lds16u(Bg0 + t * BK, &Bs[t][e0 * 512]);
        gl_lds16u(Bg1 + t * BK, &Bs[t][e1 * 512]);
    }
    asm volatile("s_waitcnt vmcnt(4)" ::: "memory");   // tile 0 resident, tile 1 in flight
    __builtin_amdgcn_s_barrier();

    #pragma unroll 1
    for (int c = 0; c < 32; ++c) {
        if (c + 2 < 32) {
            int s2 = (c + 2) % 3;
            int kt2 = (c + 2) * BK;
            gl_lds16u(Ag0 + kt2, &As[s2][e0 * 512]);
            gl_lds16u(Ag1 + kt2, &As[s2][e1 * 512]);
            gl_lds16u(Bg0 + kt2, &Bs[s2][e0 * 512]);
            gl_lds16u(Bg1 + kt2, &Bs[s2][e1 * 512]);
        }
        int cs = c % 3;
        short8 af[8], bf[4];
        #pragma unroll
        for (int mi = 0; mi < 8; mi++)
            af[mi] = *(const short8*)&As[cs][(wm * 128 + mi * 16 + l15) * BK + quad * 8];
        #pragma unroll
        for (int ni = 0; ni < 4; ni++)
            bf[ni] = *(const short8*)&Bs[cs][(wn * 64 + ni * 16 + l15) * BK + quad * 8];
        #pragma unroll
        for (int mi = 0; mi < 8; mi++)
            #pragma unroll
            for (int ni = 0; ni < 4; ni++)
                acc[mi][ni] = __builtin_amdgcn_mfma_f32_16x16x32_bf16(
                    af[mi], bf[ni], acc[mi][ni], 0, 0, 0);
        if (c < 30) {
            asm volatile("s_waitcnt vmcnt(4)" ::: "memory");
            __builtin_amdgcn_s_barrier();
        } else if (c == 30) {
            asm volatile("s_waitcnt vmcnt(0)" ::: "memory");
            __builtin_amdgcn_s_barrier();
        }
    }

    #pragma unroll
    for (int mi = 0; mi < 8; mi++)
        #pragma unroll
        for (int ni = 0; ni < 4; ni++)
            #pragma unroll
            for (int r = 0; r < 4; r++) {
                int row = bm * 256 + wm * 128 + mi * 16 + quad * 4 + r;
                int col = bn * 256 + wn * 64 + ni * 16 + l15;
                outF[(size_t)(col >> 10) * planeStride + (size_t)row * 1024 + (col & 1023)]
                    = acc[mi][ni][r];
            }
}

// ---------------- causal depthwise conv(k=4) + silu (+ l2norm for q/k, q/=8) ----------------
__global__ void gdn_conv(const float* __restrict__ pre,
                         const float* __restrict__ cqw, const float* __restrict__ cqb,
                         const float* __restrict__ ckw, const float* __restrict__ ckb,
                         const float* __restrict__ cvw, const float* __restrict__ cvb,
                         float* __restrict__ qn, float* __restrict__ kn, float* __restrict__ vn) {
    int m = blockIdx.x;
    int which = blockIdx.y;        // 0:q 1:k 2:v
    int t = m & (TSEQ - 1);
    const float* cw = (which == 0) ? cqw : (which == 1) ? ckw : cvw;
    const float* cb = (which == 0) ? cqb : (which == 1) ? ckb : cvb;
    float* dst = (which == 0) ? qn : (which == 1) ? kn : vn;
    int c = threadIdx.x * 4;       // 4 consecutive channels

    float w[4][4];
    #pragma unroll
    for (int i = 0; i < 4; i++) {
        float4 t4 = ((const float4*)cw)[c + i];   // taps of channel c+i
        w[i][0] = t4.x; w[i][1] = t4.y; w[i][2] = t4.z; w[i][3] = t4.w;
    }
    float4 bias = ((const float4*)cb)[threadIdx.x];
    float y[4] = {bias.x, bias.y, bias.z, bias.w};

    const float* src = pre + (size_t)which * PLANE + (size_t)m * DMODEL + c;
    #pragma unroll
    for (int j = 0; j < 4; j++) {
        int tt = t - 3 + j;
        if (tt >= 0) {
            float4 xv = *(const float4*)(src + (long)(j - 3) * DMODEL);
            y[0] += xv.x * w[0][j];
            y[1] += xv.y * w[1][j];
            y[2] += xv.z * w[2][j];
            y[3] += xv.w * w[3][j];
        }
    }
    #pragma unroll
    for (int i = 0; i < 4; i++) y[i] = silu_f(y[i]);

    if (which < 2) {   // l2norm over 64-channel head groups (16 consecutive lanes)
        float ss = y[0]*y[0] + y[1]*y[1] + y[2]*y[2] + y[3]*y[3];
        ss += __shfl_xor(ss, 1);
        ss += __shfl_xor(ss, 2);
        ss += __shfl_xor(ss, 4);
        ss += __shfl_xor(ss, 8);
        float sc = rsqrtf(ss + 1e-6f);
        if (which == 0) sc *= 0.125f;   // q /= sqrt(d)
        #pragma unroll
        for (int i = 0; i < 4; i++) y[i] *= sc;
    }
    float4 o; o.x = y[0]; o.y = y[1]; o.z = y[2]; o.w = y[3];
    ((float4*)(dst + (size_t)m * 1024))[threadIdx.x] = o;
}

// ======================= chunked delta rule (WY / UT transform), C = 64 =======================
// MFMA split-bf16 version, LDS-dieted to ~74 KB -> 2 blocks/CU (was 131 KB -> 1 block/CU).
// Overlays (arithmetic bitwise-identical to previous version):
//   bufA : phases 0-1 = K split (natural) ; after phase-1 barrier = -strict_tril(M) split
//   bufKT: phases 0-2 = Xs (16x132 f32 per-strip RHS, re-staged from global each strip)
//                       + MmDiag (fp32 diag blocks) ; phase 3 = K^T split (rebuilt from kn)
// Outputs unchanged: WTst[u][s] bf16; U0st[s][j] bf16; Pst = PT[u][a] fp32; Rst = RT[j][a] fp32.
__global__ __launch_bounds__(256, 2) void gdn_chunk(
    const float* __restrict__ kn, const float* __restrict__ vn,
    const float* __restrict__ betaT,
    ushort* __restrict__ WTst, ushort* __restrict__ U0st,
    float* __restrict__ Pst, float* __restrict__ Rst)
{
    __shared__ __align__(16) ushort bufA[2 * 4608];    // 18,432 B: K split -> Mneg split
    __shared__ __align__(16) ushort bufKT[2 * 4608];   // 18,432 B: Xs+MmDiag -> K^T split
    __shared__ __align__(16) ushort XThi[128 * 72];    // 18,432 B
    __shared__ __align__(16) ushort XTlo[128 * 72];    // 18,432 B
    __shared__ float bet[64];

    ushort* Khi    = bufA;          ushort* Klo    = bufA + 4608;
    ushort* Mneghi = bufA;          ushort* Mneglo = bufA + 4608;   // overlay after phase 1
    ushort* KThi   = bufKT;         ushort* KTlo   = bufKT + 4608;  // overlay in phase 3
    float*  Xs     = (float*)bufKT;                  // bytes [0, 8448)
    float*  MmDiag = (float*)(bufKT + 4608);         // bytes [9216, 14336)

    int c = blockIdx.x, bh = blockIdx.y;
    int b = bh >> 4, h = bh & 15;
    int tid = threadIdx.x;
    int w = tid >> 6, lane = tid & 63;
    int l15 = lane & 15, quad = lane >> 4;
    size_t gbase = ((size_t)(b * TSEQ + c * 64)) * DMODEL + h * 64;
    size_t u = (size_t)bh * 32 + c;

    // ---------- phase 0: beta; zero XT; load K -> split (natural only) ----------
    if (tid < 64) bet[tid] = betaT[((size_t)bh << 11) + c * 64 + tid];
    #pragma unroll
    for (int i = 0; i < 18; i++) {
        ((uint*)XThi)[tid + 256 * i] = 0u;
        ((uint*)XTlo)[tid + 256 * i] = 0u;
    }
    #pragma unroll
    for (int i = 0; i < 4; i++) {
        int idx = tid + 256 * i;
        int r = idx >> 4, c4 = (idx & 15) * 4;
        float4 kv = *(const float4*)&kn[gbase + (size_t)r * DMODEL + c4];
        ushort h0, l0, h1, l1, h2, l2, h3, l3;
        split2(kv.x, h0, l0); split2(kv.y, h1, l1);
        split2(kv.z, h2, l2); split2(kv.w, h3, l3);
        ((uint*)&Khi[r * 72 + c4])[0] = (uint)h0 | ((uint)h1 << 16);
        ((uint*)&Khi[r * 72 + c4])[1] = (uint)h2 | ((uint)h3 << 16);
        ((uint*)&Klo[r * 72 + c4])[0] = (uint)l0 | ((uint)l1 << 16);
        ((uint*)&Klo[r * 72 + c4])[1] = (uint)l2 | ((uint)l3 << 16);
    }
    __syncthreads();

    // ---------- phase 1: M = beta K K^T via MFMA; then overlay Mneg onto K ----------
    {
        f32x4 mAcc[4];
        #pragma unroll
        for (int tn = 0; tn < 4; tn++) mAcc[tn] = (f32x4){0.f, 0.f, 0.f, 0.f};
        #pragma unroll
        for (int ks = 0; ks < 2; ks++) {
            short8 aH = *(const short8*)&Khi[(16 * w + l15) * 72 + ks * 32 + quad * 8];
            short8 aL = *(const short8*)&Klo[(16 * w + l15) * 72 + ks * 32 + quad * 8];
            #pragma unroll
            for (int tn = 0; tn < 4; tn++) {
                short8 bH = *(const short8*)&Khi[(16 * tn + l15) * 72 + ks * 32 + quad * 8];
                short8 bL = *(const short8*)&Klo[(16 * tn + l15) * 72 + ks * 32 + quad * 8];
                mAcc[tn] = __builtin_amdgcn_mfma_f32_16x16x32_bf16(aH, bH, mAcc[tn], 0, 0, 0);
                mAcc[tn] = __builtin_amdgcn_mfma_f32_16x16x32_bf16(aH, bL, mAcc[tn], 0, 0, 0);
                mAcc[tn] = __builtin_amdgcn_mfma_f32_16x16x32_bf16(aL, bH, mAcc[tn], 0, 0, 0);
            }
        }
        __syncthreads();   // all waves done reading K before the overlay write
        #pragma unroll
        for (int tn = 0; tn < 4; tn++) {
            #pragma unroll
            for (int r = 0; r < 4; r++) {
                int row = 16 * w + quad * 4 + r;
                int col = tn * 16 + l15;
                float val = mAcc[tn][r] * bet[row];
                ushort hh = 0, ll = 0;
                if (col < row) {
                    float nv = -val;
                    hh = f2bf(nv);
                    ll = f2bf(nv - bf2f(hh));
                }
                Mneghi[row * 72 + col] = hh;
                Mneglo[row * 72 + col] = ll;
                if (tn == w) MmDiag[w * 320 + (row & 15) * 20 + l15] = val;
            }
        }
    }
    __syncthreads();

    // ---------- phase 2: 4 strips: stage RHS from global -> MFMA update -> solve ----------
    #pragma unroll 1
    for (int st = 0; st < 4; st++) {
        int tb = st * 16;
        {   // stage this strip's RHS: Xs[rl][0:64]=beta*K, [64:128]=beta*V (bitwise = old Xf)
            int rl = tid >> 4, c4 = (tid & 15) * 4;
            int r = tb + rl;
            float br = bet[r];
            float4 kv = *(const float4*)&kn[gbase + (size_t)r * DMODEL + c4];
            float4 vv = *(const float4*)&vn[gbase + (size_t)r * DMODEL + c4];
            float4 xk; xk.x = br * kv.x; xk.y = br * kv.y; xk.z = br * kv.z; xk.w = br * kv.w;
            float4 xv; xv.x = br * vv.x; xv.y = br * vv.y; xv.z = br * vv.z; xv.w = br * vv.w;
            *(float4*)&Xs[rl * 132 + c4] = xk;
            *(float4*)&Xs[rl * 132 + 64 + c4] = xv;
        }
        __syncthreads();   // Xs staged (and prev strip's solver reads finished before overwrite)

        if (st) {
            // strip update: X_strip -= M[strip][:] * Xsolved (Mneg = -M, unsolved XT rows = 0)
            f32x4 acc2[2];
            #pragma unroll
            for (int e = 0; e < 2; e++) {
                int tn = 2 * w + e;
                #pragma unroll
                for (int r = 0; r < 4; r++)
                    acc2[e][r] = Xs[(quad * 4 + r) * 132 + tn * 16 + l15];
            }
            #pragma unroll
            for (int ks = 0; ks < 2; ks++) {
                short8 aH = *(const short8*)&Mneghi[(tb + l15) * 72 + ks * 32 + quad * 8];
                short8 aL = *(const short8*)&Mneglo[(tb + l15) * 72 + ks * 32 + quad * 8];
                #pragma unroll
                for (int e = 0; e < 2; e++) {
                    int tn = 2 * w + e;
                    short8 bH = *(const short8*)&XThi[(tn * 16 + l15) * 72 + ks * 32 + quad * 8];
                    short8 bL = *(const short8*)&XTlo[(tn * 16 + l15) * 72 + ks * 32 + quad * 8];
                    acc2[e] = __builtin_amdgcn_mfma_f32_16x16x32_bf16(aH, bH, acc2[e], 0, 0, 0);
                    acc2[e] = __builtin_amdgcn_mfma_f32_16x16x32_bf16(aH, bL, acc2[e], 0, 0, 0);
                    acc2[e] = __builtin_amdgcn_mfma_f32_16x16x32_bf16(aL, bH, acc2[e], 0, 0, 0);
                }
            }
            #pragma unroll
            for (int e = 0; e < 2; e++) {
                int tn = 2 * w + e;
                #pragma unroll
                for (int r = 0; r < 4; r++)
                    Xs[(quad * 4 + r) * 132 + tn * 16 + l15] = acc2[e][r];
            }
            __syncthreads();   // updated strip visible to the solver
        }

        if (tid < 128) {     // column j solver (2 waves)
            const int j = tid;
            const float* MD = &MmDiag[st * 320];   // [16][20]
            float xr[16];
            #pragma unroll
            for (int sb = 0; sb < 4; sb++) {
                float b4[4];
                #pragma unroll
                for (int i = 0; i < 4; i++)
                    b4[i] = Xs[(sb * 4 + i) * 132 + j];
                #pragma unroll
                for (int u4 = 0; u4 < sb; u4++) {
                    #pragma unroll
                    for (int i = 0; i < 4; i++) {
                        float4 m4 = *(const float4*)&MD[(sb * 4 + i) * 20 + u4 * 4];
                        b4[i] -= m4.x * xr[u4 * 4 + 0] + m4.y * xr[u4 * 4 + 1]
                               + m4.z * xr[u4 * 4 + 2] + m4.w * xr[u4 * 4 + 3];
                    }
                }
                float x0 = b4[0];
                float x1 = b4[1] - MD[(sb * 4 + 1) * 20 + sb * 4 + 0] * x0;
                float x2 = b4[2] - MD[(sb * 4 + 2) * 20 + sb * 4 + 0] * x0
                                 - MD[(sb * 4 + 2) * 20 + sb * 4 + 1] * x1;
                float x3 = b4[3] - MD[(sb * 4 + 3) * 20 + sb * 4 + 0] * x0
                                 - MD[(sb * 4 + 3) * 20 + sb * 4 + 1] * x1
                                 - MD[(sb * 4 + 3) * 20 + sb * 4 + 2] * x2;
                xr[sb * 4 + 0] = x0; xr[sb * 4 + 1] = x1;
                xr[sb * 4 + 2] = x2; xr[sb * 4 + 3] = x3;
            }
            // split + store to XT (hi/lo) and global W/U0 (hi = bf16 value)
            ushort hs[16], ls[16];
            #pragma unroll
            for (int i = 0; i < 16; i++) split2(xr[i], hs[i], ls[i]);
            uint4 ph0, ph1, pl0, pl1;
            ph0.x = (uint)hs[0] | ((uint)hs[1] << 16);  ph0.y = (uint)hs[2] | ((uint)hs[3] << 16);
            ph0.z = (uint)hs[4] | ((uint)hs[5] << 16);  ph0.w = (uint)hs[6] | ((uint)hs[7] << 16);
            ph1.x = (uint)hs[8] | ((uint)hs[9] << 16);  ph1.y = (uint)hs[10] | ((uint)hs[11] << 16);
            ph1.z = (uint)hs[12] | ((uint)hs[13] << 16); ph1.w = (uint)hs[14] | ((uint)hs[15] << 16);
            pl0.x = (uint)ls[0] | ((uint)ls[1] << 16);  pl0.y = (uint)ls[2] | ((uint)ls[3] << 16);
            pl0.z = (uint)ls[4] | ((uint)ls[5] << 16);  pl0.w = (uint)ls[6] | ((uint)ls[7] << 16);
            pl1.x = (uint)ls[8] | ((uint)ls[9] << 16);  pl1.y = (uint)ls[10] | ((uint)ls[11] << 16);
            pl1.z = (uint)ls[12] | ((uint)ls[13] << 16); pl1.w = (uint)ls[14] | ((uint)ls[15] << 16);
            *(uint4*)&XThi[j * 72 + tb] = ph0;  *(uint4*)&XThi[j * 72 + tb + 8] = ph1;
            *(uint4*)&XTlo[j * 72 + tb] = pl0;  *(uint4*)&XTlo[j * 72 + tb + 8] = pl1;
            if (j < 64) {   // W^T[u=j][s=tb..tb+15]
                ushort* wdst = WTst + u * 4096 + j * 64 + tb;
                *(uint4*)wdst = ph0; *(uint4*)(wdst + 8) = ph1;
            } else {        // U0[s=tb+i][jv=j-64]
                ushort* udst = U0st + u * 4096 + (size_t)tb * 64 + (j - 64);
                #pragma unroll
                for (int i = 0; i < 16; i++) udst[i * 64] = hs[i];
            }
        }
        __syncthreads();
    }

    // ---------- phase 3: rebuild K^T (Xs/MmDiag dead), then P^T = W^T K, R = K^T U0 ----------
    #pragma unroll
    for (int i = 0; i < 4; i++) {
        int idx = tid + 256 * i;
        int r = idx >> 4, c4 = (idx & 15) * 4;
        float4 kv = *(const float4*)&kn[gbase + (size_t)r * DMODEL + c4];
        ushort h0, l0, h1, l1, h2, l2, h3, l3;
        split2(kv.x, h0, l0); split2(kv.y, h1, l1);
        split2(kv.z, h2, l2); split2(kv.w, h3, l3);
        KThi[(c4 + 0) * 72 + r] = h0; KThi[(c4 + 1) * 72 + r] = h1;
        KThi[(c4 + 2) * 72 + r] = h2; KThi[(c4 + 3) * 72 + r] = h3;
        KTlo[(c4 + 0) * 72 + r] = l0; KTlo[(c4 + 1) * 72 + r] = l1;
        KTlo[(c4 + 2) * 72 + r] = l2; KTlo[(c4 + 3) * 72 + r] = l3;
    }
    __syncthreads();

    {
        f32x4 pAcc[4], rAcc[4];
        #pragma unroll
        for (int tn = 0; tn < 4; tn++) {
            pAcc[tn] = (f32x4){0.f, 0.f, 0.f, 0.f};
            rAcc[tn] = (f32x4){0.f, 0.f, 0.f, 0.f};
        }
        #pragma unroll
        for (int ks = 0; ks < 2; ks++) {
            short8 aH = *(const short8*)&XThi[(16 * w + l15) * 72 + ks * 32 + quad * 8]; // W^T rows
            short8 aL = *(const short8*)&XTlo[(16 * w + l15) * 72 + ks * 32 + quad * 8];
            short8 cH = *(const short8*)&KThi[(16 * w + l15) * 72 + ks * 32 + quad * 8]; // K^T rows
            short8 cL = *(const short8*)&KTlo[(16 * w + l15) * 72 + ks * 32 + quad * 8];
            #pragma unroll
            for (int tn = 0; tn < 4; tn++) {
                short8 bH = *(const short8*)&KThi[(16 * tn + l15) * 72 + ks * 32 + quad * 8];
                short8 bL = *(const short8*)&KTlo[(16 * tn + l15) * 72 + ks * 32 + quad * 8];
                pAcc[tn] = __builtin_amdgcn_mfma_f32_16x16x32_bf16(aH, bH, pAcc[tn], 0, 0, 0);
                pAcc[tn] = __builtin_amdgcn_mfma_f32_16x16x32_bf16(aH, bL, pAcc[tn], 0, 0, 0);
                pAcc[tn] = __builtin_amdgcn_mfma_f32_16x16x32_bf16(aL, bH, pAcc[tn], 0, 0, 0);
                short8 uH = *(const short8*)&XThi[(64 + 16 * tn + l15) * 72 + ks * 32 + quad * 8];
                short8 uL = *(const short8*)&XTlo[(64 + 16 * tn + l15) * 72 + ks * 32 + quad * 8];
                rAcc[tn] = __builtin_amdgcn_mfma_f32_16x16x32_bf16(cH, uH, rAcc[tn], 0, 0, 0);
                rAcc[tn] = __builtin_amdgcn_mfma_f32_16x16x32_bf16(cH, uL, rAcc[tn], 0, 0, 0);
                rAcc[tn] = __builtin_amdgcn_mfma_f32_16x16x32_bf16(cL, uH, rAcc[tn], 0, 0, 0);
            }
        }
        float* Po = Pst + u * 4096;
        float* Ro = Rst + u * 4096;
        #pragma unroll
        for (int tn = 0; tn < 4; tn++) {
            #pragma unroll
            for (int r = 0; r < 4; r++) {
                int row = 16 * w + quad * 4 + r;
                int col = tn * 16 + l15;
                Po[row * 64 + col] = pAcc[tn][r];   // PT[u][a]
                Ro[col * 64 + row] = rAcc[tn][r];   // RT[j][a]  (transposed for sstep slicing)
            }
        }
    }
}

// serial cross-chunk state propagation: S <- S - P*S + R ; records S0 per chunk.
__global__ __launch_bounds__(256) void gdn_sstep(const float* __restrict__ Pst,
                                                 const float* __restrict__ Rst,
                                                 float* __restrict__ S0st)
{
    __shared__ float PTl[3][4096];      // PT[u][a] per chunk
    __shared__ float Rl[3][1024];       // RT slice [16 j][64 a]
    __shared__ float SshT[2][16][72];   // S^T: SshT[j][a] = S[a][j]

    int bh = blockIdx.x >> 2, cg = blockIdx.x & 3;
    int tid = threadIdx.x;
    int t0 = (tid & 15) * 4;            // a-rows owned (4)
    int j  = tid >> 4;                  // local v-col 0..15
    int jg = cg * 16 + j;
    int wv = tid >> 6, ln = tid & 63;

    size_t ubase = (size_t)bh * 32 * 4096;

    *(float4*)&SshT[0][j][t0] = (float4){0.f, 0.f, 0.f, 0.f};

    #pragma unroll
    for (int t = 0; t < 2; t++) {
        size_t ub = ubase + (size_t)t * 4096;
        #pragma unroll
        for (int q = 0; q < 4; q++)
            gl_lds16(Pst + ub + (wv * 4 + q) * 256 + ln * 4, &PTl[t][(wv * 4 + q) * 256]);
        gl_lds16(Rst + ub + cg * 1024 + wv * 256 + ln * 4, &Rl[t][wv * 256]);
    }
    asm volatile("s_waitcnt vmcnt(5)" ::: "memory");
    asm volatile("s_waitcnt lgkmcnt(0)" ::: "memory");
    __builtin_amdgcn_s_barrier();

    int cur3 = 0;
    #pragma unroll 1
    for (int c = 0; c < 32; ++c) {
        int cur = c & 1, nxt = cur ^ 1;
        if (c + 2 < 32) {
            int b3 = cur3 + 2; if (b3 >= 3) b3 -= 3;
            size_t ub2 = ubase + (size_t)(c + 2) * 4096;
            #pragma unroll
            for (int q = 0; q < 4; q++)
                gl_lds16(Pst + ub2 + (wv * 4 + q) * 256 + ln * 4, &PTl[b3][(wv * 4 + q) * 256]);
            gl_lds16(Rst + ub2 + cg * 1024 + wv * 256 + ln * 4, &Rl[b3][wv * 256]);
        }
        float4 sold = *(const float4*)&SshT[cur][j][t0];
        size_t ub = ubase + (size_t)c * 4096;
        S0st[ub + (size_t)(t0 + 0) * 64 + jg] = sold.x;
        S0st[ub + (size_t)(t0 + 1) * 64 + jg] = sold.y;
        S0st[ub + (size_t)(t0 + 2) * 64 + jg] = sold.z;
        S0st[ub + (size_t)(t0 + 3) * 64 + jg] = sold.w;
        float4 racc = *(const float4*)&Rl[cur3][j * 64 + t0];
        float sub0 = 0.f, sub1 = 0.f, sub2 = 0.f, sub3 = 0.f;
        #pragma unroll
        for (int u4 = 0; u4 < 16; u4++) {
            float4 sv = *(const float4*)&SshT[cur][j][u4 * 4];
            #pragma unroll
            for (int e = 0; e < 4; e++) {
                float4 pt = *(const float4*)&PTl[cur3][(u4 * 4 + e) * 64 + t0];
                float s1 = (e == 0) ? sv.x : (e == 1) ? sv.y : (e == 2) ? sv.z : sv.w;
                sub0 = fmaf(pt.x, s1, sub0);
                sub1 = fmaf(pt.y, s1, sub1);
                sub2 = fmaf(pt.z, s1, sub2);
                sub3 = fmaf(pt.w, s1, sub3);
            }
        }
        float4 snew;
        snew.x = sold.x + racc.x - sub0;
        snew.y = sold.y + racc.y - sub1;
        snew.z = sold.z + racc.z - sub2;
        snew.w = sold.w + racc.w - sub3;
        *(float4*)&SshT[nxt][j][t0] = snew;
        if (c == 0)       { asm volatile("s_waitcnt vmcnt(9)"  ::: "memory"); }
        else if (c < 30)  { asm volatile("s_waitcnt vmcnt(13)" ::: "memory"); }
        else if (c == 30) { asm volatile("s_waitcnt vmcnt(8)"  ::: "memory"); }
        asm volatile("s_waitcnt lgkmcnt(0)" ::: "memory");
        __builtin_amdgcn_s_barrier();
        cur3 += 1; if (cur3 >= 3) cur3 -= 3;
    }
}

// output pass (MFMA, split-bf16): O = Q S0 + tril_incl(Q K^T) (U0 - W S0)
__global__ __launch_bounds__(256) void gdn_opass(
    const float* __restrict__ qn, const float* __restrict__ kn,
    const float* __restrict__ S0st, const ushort* __restrict__ WTst,
    const ushort* __restrict__ U0st, float* __restrict__ otmp2)
{
    __shared__ ushort pool[36864];          // 73728 B
    ushort* Qhi  = pool;                    // [t][d] pitch 72
    ushort* Qlo  = pool + 4608;
    ushort* Khi  = pool + 2 * 4608;         // [s][d]
    ushort* Klo  = pool + 3 * 4608;
    ushort* SThi = pool + 4 * 4608;         // S0^T [jv][a]
    ushort* STlo = pool + 5 * 4608;
    ushort* Wn   = pool + 6 * 4608;         // -W [s][u]
    ushort* Uu   = pool + 7 * 4608;         // U0 [s][jv] pitch 64
    ushort* Ghi  = Qhi;  ushort* Glo  = Qlo;   // overlay: masked G [t][s]
    ushort* EThi = Khi;  ushort* ETlo = Klo;   // overlay: E^T [jv][s]

    int c = blockIdx.x, bh = blockIdx.y;
    int b = bh >> 4, h = bh & 15;
    int tid = threadIdx.x;
    int w = tid >> 6, lane = tid & 63;
    int l15 = lane & 15, quad = lane >> 4;
    size_t gbase = ((size_t)(b * TSEQ + c * 64)) * DMODEL + h * 64;
    size_t u = (size_t)bh * 32 + c;

    #pragma unroll
    for (int i = 0; i < 4; i++) {
        int idx = tid + 256 * i;
        int r = idx >> 4, c4 = (idx & 15) * 4;
        float4 qv = *(const float4*)&qn[gbase + (size_t)r * DMODEL + c4];
        float4 kv = *(const float4*)&kn[gbase + (size_t)r * DMODEL + c4];
        float4 sv = *(const float4*)&S0st[u * 4096 + (size_t)idx * 4];
        ushort h0, l0, h1, l1, h2, l2, h3, l3;
        split2(qv.x, h0, l0); split2(qv.y, h1, l1);
        split2(qv.z, h2, l2); split2(qv.w, h3, l3);
        ((uint*)&Qhi[r * 72 + c4])[0] = (uint)h0 | ((uint)h1 << 16);
        ((uint*)&Qhi[r * 72 + c4])[1] = (uint)h2 | ((uint)h3 << 16);
        ((uint*)&Qlo[r * 72 + c4])[0] = (uint)l0 | ((uint)l1 << 16);
        ((uint*)&Qlo[r * 72 + c4])[1] = (uint)l2 | ((uint)l3 << 16);
        split2(kv.x, h0, l0); split2(kv.y, h1, l1);
        split2(kv.z, h2, l2); split2(kv.w, h3, l3);
        ((uint*)&Khi[r * 72 + c4])[0] = (uint)h0 | ((uint)h1 << 16);
        ((uint*)&Khi[r * 72 + c4])[1] = (uint)h2 | ((uint)h3 << 16);
        ((uint*)&Klo[r * 72 + c4])[0] = (uint)l0 | ((uint)l1 << 16);
        ((uint*)&Klo[r * 72 + c4])[1] = (uint)l2 | ((uint)l3 << 16);
        split2(sv.x, h0, l0); split2(sv.y, h1, l1);
        split2(sv.z, h2, l2); split2(sv.w, h3, l3);
        SThi[(c4 + 0) * 72 + r] = h0; STlo[(c4 + 0) * 72 + r] = l0;
        SThi[(c4 + 1) * 72 + r] = h1; STlo[(c4 + 1) * 72 + r] = l1;
        SThi[(c4 + 2) * 72 + r] = h2; STlo[(c4 + 2) * 72 + r] = l2;
        SThi[(c4 + 3) * 72 + r] = h3; STlo[(c4 + 3) * 72 + r] = l3;
    }
    #pragma unroll
    for (int i = 0; i < 2; i++) {
        int idx = tid + 256 * i;
        uint4 w8 = ((const uint4*)(WTst + u * 4096))[idx];    // WT[u][s], 8 along s
        int ur = idx >> 3, t8 = (idx & 7) * 8;
        uint v0 = w8.x ^ 0x80008000u, v1 = w8.y ^ 0x80008000u;
        uint v2 = w8.z ^ 0x80008000u, v3 = w8.w ^ 0x80008000u;
        Wn[(t8 + 0) * 72 + ur] = (ushort)v0; Wn[(t8 + 1) * 72 + ur] = (ushort)(v0 >> 16);
        Wn[(t8 + 2) * 72 + ur] = (ushort)v1; Wn[(t8 + 3) * 72 + ur] = (ushort)(v1 >> 16);
        Wn[(t8 + 4) * 72 + ur] = (ushort)v2; Wn[(t8 + 5) * 72 + ur] = (ushort)(v2 >> 16);
        Wn[(t8 + 6) * 72 + ur] = (ushort)v3; Wn[(t8 + 7) * 72 + ur] = (ushort)(v3 >> 16);
        ((uint4*)Uu)[idx] = ((const uint4*)(U0st + u * 4096))[idx];
    }
    __syncthreads();

    f32x4 accG[4], accO[4], accE[4];
    #pragma unroll
    for (int tn = 0; tn < 4; tn++) {
        accG[tn] = (f32x4){0.f, 0.f, 0.f, 0.f};
        accO[tn] = (f32x4){0.f, 0.f, 0.f, 0.f};
        #pragma unroll
        for (int r = 0; r < 4; r++)
            accE[tn][r] = bf2f(Uu[(16 * w + quad * 4 + r) * 64 + tn * 16 + l15]);
    }
    #pragma unroll
    for (int ks = 0; ks < 2; ks++) {
        int ko = ks * 32 + quad * 8;
        short8 qH = *(const short8*)&Qhi[(16 * w + l15) * 72 + ko];
        short8 qL = *(const short8*)&Qlo[(16 * w + l15) * 72 + ko];
        short8 wA = *(const short8*)&Wn [(16 * w + l15) * 72 + ko];
        #pragma unroll
        for (int tn = 0; tn < 4; tn++) {
            short8 kH = *(const short8*)&Khi [(16 * tn + l15) * 72 + ko];
            short8 kL = *(const short8*)&Klo [(16 * tn + l15) * 72 + ko];
            short8 sH = *(const short8*)&SThi[(16 * tn + l15) * 72 + ko];
            short8 sL = *(const short8*)&STlo[(16 * tn + l15) * 72 + ko];
            accG[tn] = __builtin_amdgcn_mfma_f32_16x16x32_bf16(qH, kH, accG[tn], 0, 0, 0);
            accG[tn] = __builtin_amdgcn_mfma_f32_16x16x32_bf16(qH, kL, accG[tn], 0, 0, 0);
            accG[tn] = __builtin_amdgcn_mfma_f32_16x16x32_bf16(qL, kH, accG[tn], 0, 0, 0);
            accO[tn] = __builtin_amdgcn_mfma_f32_16x16x32_bf16(qH, sH, accO[tn], 0, 0, 0);
            accO[tn] = __builtin_amdgcn_mfma_f32_16x16x32_bf16(qH, sL, accO[tn], 0, 0, 0);
            accO[tn] = __builtin_amdgcn_mfma_f32_16x16x32_bf16(qL, sH, accO[tn], 0, 0, 0);
            accE[tn] = __builtin_amdgcn_mfma_f32_16x16x32_bf16(wA, sH, accE[tn], 0, 0, 0);
            accE[tn] = __builtin_amdgcn_mfma_f32_16x16x32_bf16(wA, sL, accE[tn], 0, 0, 0);
        }
    }
    __syncthreads();

    #pragma unroll
    for (int tn = 0; tn < 4; tn++) {
        #pragma unroll
        for (int r = 0; r < 4; r++) {
            int row = 16 * w + quad * 4 + r;
            int col = tn * 16 + l15;
            float gv = (col <= row) ? accG[tn][r] : 0.f;
            ushort gh, gl; split2(gv, gh, gl);
            Ghi[row * 72 + col] = gh; Glo[row * 72 + col] = gl;
            ushort eh, el; split2(accE[tn][r], eh, el);
            EThi[col * 72 + row] = eh; ETlo[col * 72 + row] = el;
        }
    }
    __syncthreads();

    #pragma unroll
    for (int ks = 0; ks < 2; ks++) {
        int ko = ks * 32 + quad * 8;
        short8 gH = *(const short8*)&Ghi[(16 * w + l15) * 72 + ko];
        short8 gL = *(const short8*)&Glo[(16 * w + l15) * 72 + ko];
        #pragma unroll
        for (int tn = 0; tn < 4; tn++) {
            short8 eH = *(const short8*)&EThi[(16 * tn + l15) * 72 + ko];
            short8 eL = *(const short8*)&ETlo[(16 * tn + l15) * 72 + ko];
            accO[tn] = __builtin_amdgcn_mfma_f32_16x16x32_bf16(gH, eH, accO[tn], 0, 0, 0);
            accO[tn] = __builtin_amdgcn_mfma_f32_16x16x32_bf16(gH, eL, accO[tn], 0, 0, 0);
            accO[tn] = __builtin_amdgcn_mfma_f32_16x16x32_bf16(gL, eH, accO[tn], 0, 0, 0);
        }
    }

    #pragma unroll
    for (int tn = 0; tn < 4; tn++) {
        #pragma unroll
        for (int r = 0; r < 4; r++) {
            int row = 16 * w + quad * 4 + r;
            int col = tn * 16 + l15;
            otmp2[(((size_t)bh * 16 + (col >> 2)) * TSEQ + c * 64 + row) * 4 + (col & 3)]
                = accO[tn][r];
        }
    }
}

// ---------------- RMSNorm * nw * silu(gate) -> bf16 ----------------
__global__ void gdn_fuse(const float* __restrict__ otmp2, const float* __restrict__ pre,
                         const float* __restrict__ nw, ushort* __restrict__ ofused) {
    int m = blockIdx.x;
    int b = m >> 11, t = m & (TSEQ - 1);
    int tid = threadIdx.x;
    float4 o = ((const float4*)otmp2)[((size_t)((b * NH + (tid >> 4)) * 16 + (tid & 15))) * TSEQ + t];
    float ss = o.x*o.x + o.y*o.y + o.z*o.z + o.w*o.w;
    ss += __shfl_xor(ss, 1);
    ss += __shfl_xor(ss, 2);
    ss += __shfl_xor(ss, 4);
    ss += __shfl_xor(ss, 8);
    float r = rsqrtf(ss * (1.f / 64.f) + 1e-5f);
    float4 nwv = ((const float4*)nw)[tid & 15];
    float4 g = ((const float4*)(pre + 3 * (size_t)PLANE + (size_t)m * DMODEL))[tid];
    ushort4 out;
    out.x = f2bf(o.x * r * nwv.x * silu_f(g.x));
    out.y = f2bf(o.y * r * nwv.y * silu_f(g.y));
    out.z = f2bf(o.z * r * nwv.z * silu_f(g.z));
    out.w = f2bf(o.w * r * nwv.w * silu_f(g.w));
    ((ushort4*)ofused)[m * 256 + tid] = out;
}

extern "C" void kernel_launch(void* const* d_in, const int* in_sizes, int n_in,
                              void* d_out, int out_size, void* d_ws, size_t ws_size,
                              hipStream_t stream) {
    const float* x    = (const float*)d_in[0];
    const float* Wq   = (const float*)d_in[1];
    const float* Wk   = (const float*)d_in[2];
    const float* Wv   = (const float*)d_in[3];
    const float* Wo   = (const float*)d_in[4];
    const float* Wg   = (const float*)d_in[5];
    const float* Wb   = (const float*)d_in[6];
    const float* cq_w = (const float*)d_in[7];
    const float* cq_b = (const float*)d_in[8];
    const float* ck_w = (const float*)d_in[9];
    const float* ck_b = (const float*)d_in[10];
    const float* cv_w = (const float*)d_in[11];
    const float* cv_b = (const float*)d_in[12];
    const float* nw   = (const float*)d_in[13];

    char* ws = (char*)d_ws;
    ushort* xb     = (ushort*)(ws);                       // 8 MB; reused as WT bf16 after GEMM
    ushort* wt     = (ushort*)(ws + 8388608);             // 10 MB (5 transposed bf16 weights)
    float*  pre    = (float*)(ws + 18874368);             // 64 MB: 4 planes [4096][1024] q|k|v|g
    float*  qn     = (float*)(ws + 85983232);             // 16 MB
    float*  kn     = (float*)(ws + 102760448);            // 16 MB
    float*  vn     = (float*)(ws + 119537664);            // 16 MB
    float*  betaT  = (float*)(ws + 136314880);            // 256 KB
    float*  otmp2  = (float*)(ws + 136577024);            // 16 MB
    ushort* ofused = (ushort*)(ws + 153354240);           // 8 MB; doubles as U0 bf16 earlier

    // dead-region reuse (all safely ordered by stream):
    float*  Pst  = pre;               // q-plane, dead after conv
    float*  Rst  = pre + PLANE;       // k-plane, dead after conv
    float*  S0st = pre + 2 * PLANE;   // v-plane, dead after conv
    ushort* WTst = xb;                // dead after pre-GEMM
    ushort* U0st = ofused;            // written later by fuse (after opass consumes it)

    // 1. x -> bf16
    gdn_cvt_x<<<4096, 256, 0, stream>>>(x, xb);
    // 2. transpose+convert 5 weights
    gdn_cvt_w<<<dim3(32, 32, 5), dim3(32, 8), 0, stream>>>(Wq, Wk, Wv, Wg, Wo, wt);
    // 3. betaT (fp32 exact)
    gdn_beta<<<256, 256, 0, stream>>>(x, Wb, betaT);
    // 4. fused q/k/v/g pre-activation GEMM -> 4 planes (256^2 counted-vmcnt pipeline)
    gdn_gemm256<<<dim3(16, 16), 512, 0, stream>>>(xb, wt, pre, (size_t)PLANE);
    // 5. conv + silu (+ l2norm)
    gdn_conv<<<dim3(4096, 3), 256, 0, stream>>>(pre, cq_w, cq_b, ck_w, ck_b, cv_w, cv_b,
                                                qn, kn, vn);
    // 6a. chunk-parallel precompute (M solve, W/U0, P/R) — MFMA split-bf16, 2 blocks/CU
    gdn_chunk<<<dim3(32, 32), 256, 0, stream>>>(kn, vn, betaT, WTst, U0st, Pst, Rst);
    // 6b. serial state propagation (32 chunk steps, counted-vmcnt pipeline)
    gdn_sstep<<<128, 256, 0, stream>>>(Pst, Rst, S0st);
    // 6c. chunk-parallel outputs (MFMA split-bf16)
    gdn_opass<<<dim3(32, 32), 256, 0, stream>>>(qn, kn, S0st, WTst, U0st, otmp2);
    // 7. RMSNorm * nw * silu(gate) -> bf16
    gdn_fuse<<<4096, 256, 0, stream>>>(otmp2, pre, nw, ofused);
    // 8. final GEMM -> d_out (fp32 output), 128^2 (N=1024 -> 256 blocks)
    gdn_gemm<<<dim3(32, 8), 256, 0, stream>>>(ofused, wt + 4 * 1024 * 1024,
                                              (float*)d_out, (size_t)0);
}